// Round 1
// baseline (2952.751 us; speedup 1.0000x reference)
//
#include <hip/hip_runtime.h>
#include <math.h>

constexpr float BN_EPS_C = 1e-5f;
constexpr float RES_SCALE_C = 0.70710678118654752f;
constexpr float GAMMA_C = 1.5f;

// ---------------------------------------------------------------- embed + input BN
__global__ void embed_bn_kernel(const float* __restrict__ x_num,
                                const int* __restrict__ x_cat,
                                const float* __restrict__ emb_W,
                                const float* __restrict__ in_bn,
                                float* __restrict__ x)
{
    const int s = blockIdx.x;
    const int j = threadIdx.x;   // 0..319
    float v;
    if (j < 64) {
        v = x_num[(size_t)s * 64 + j];
    } else {
        const int c = (j - 64) >> 4, e = (j - 64) & 15;
        const int idx = x_cat[(size_t)s * 16 + c];
        v = emb_W[(size_t)(c * 1000 + idx) * 16 + e];
    }
    const float sc = in_bn[j], bb = in_bn[320 + j], mm = in_bn[640 + j], vv = in_bn[960 + j];
    const float scale = sc / sqrtf(vv + BN_EPS_C);
    x[(size_t)s * 320 + j] = (v - mm) * scale + bb;
}

// ---------------------------------------------------------------- fused GEMM + BN + GLU (+res) (+split epilogue)
// C(64x256) = A(64xK) @ W(K x 256); per-block 64 samples, 256 threads, 8x8 acc.
// wmode: 0 = write 128-wide out; 1 = write a only; 2 = a + dsum=relu(d); 3 = a + dsum+=relu(d)
template<int K, bool MASK>
__global__ __launch_bounds__(256, 3)
void glu_gemm(const float* __restrict__ A, const float* __restrict__ maskg,
              const float* __restrict__ W, const float* __restrict__ bias,
              const float* __restrict__ bn, float* __restrict__ out,
              float* __restrict__ a_out, float* __restrict__ dsum,
              int resid, int wmode)
{
    constexpr int KC = 32;
    __shared__ float As[KC][68];     // transposed A tile, +4 pad keeps 16B align & breaks conflicts
    __shared__ float Ws[KC][256];
    const int t = threadIdx.x;
    const int s0 = blockIdx.x * 64;
    const int tc = t & 31, tr = t >> 5;
    const int co = tc * 4;

    float acc[8][8];
#pragma unroll
    for (int i = 0; i < 8; ++i)
#pragma unroll
        for (int j = 0; j < 8; ++j) acc[i][j] = 0.f;

    // BN fold: y = h*scale + shift  (per this thread's 4 o-channels + 4 g-channels)
    float sc_o[4], sh_o[4], sc_g[4], sh_g[4], bi_o[4], bi_g[4];
#pragma unroll
    for (int j = 0; j < 4; ++j) {
        int c1 = co + j;
        float sc = bn[c1] / sqrtf(bn[768 + c1] + BN_EPS_C);
        sc_o[j] = sc; sh_o[j] = bn[256 + c1] - bn[512 + c1] * sc;
        int c2 = 128 + co + j;
        sc = bn[c2] / sqrtf(bn[768 + c2] + BN_EPS_C);
        sc_g[j] = sc; sh_g[j] = bn[256 + c2] - bn[512 + c2] * sc;
        bi_o[j] = bias[c1]; bi_g[j] = bias[c2];
    }

    const int la_s = t >> 2;          // 0..63 : sample row this thread loads
    const int la_k = (t & 3) * 4;     // 0,4,8,12
    const float* Arow = A + (size_t)(s0 + la_s) * K;
    const float* mrow = MASK ? (maskg + (size_t)(s0 + la_s) * 80) : nullptr;

    for (int kc = 0; kc < K; kc += KC) {
        __syncthreads();
#pragma unroll
        for (int it = 0; it < 2; ++it) {
            const int kk = la_k + it * 16;
            const int k = kc + kk;
            float4 v = *(const float4*)(Arow + k);
            if (MASK) {
                if (k < 64) {
                    float4 m = *(const float4*)(mrow + k);
                    v.x *= m.x; v.y *= m.y; v.z *= m.z; v.w *= m.w;
                } else {
                    float m = mrow[64 + ((k - 64) >> 4)];
                    v.x *= m; v.y *= m; v.z *= m; v.w *= m;
                }
            }
            As[kk + 0][la_s] = v.x; As[kk + 1][la_s] = v.y;
            As[kk + 2][la_s] = v.z; As[kk + 3][la_s] = v.w;
        }
#pragma unroll
        for (int it = 0; it < 8; ++it) {
            const int kk = (t >> 6) + it * 4;
            const int c = (t & 63) * 4;
            *(float4*)&Ws[kk][c] = *(const float4*)(W + (size_t)(kc + kk) * 256 + c);
        }
        __syncthreads();
#pragma unroll 4
        for (int kk = 0; kk < KC; ++kk) {
            float av[8], wv[8];
            float4 u0 = *(const float4*)&As[kk][tr * 8];
            float4 u1 = *(const float4*)&As[kk][tr * 8 + 4];
            av[0] = u0.x; av[1] = u0.y; av[2] = u0.z; av[3] = u0.w;
            av[4] = u1.x; av[5] = u1.y; av[6] = u1.z; av[7] = u1.w;
            float4 w0 = *(const float4*)&Ws[kk][co];
            float4 w1 = *(const float4*)&Ws[kk][128 + co];
            wv[0] = w0.x; wv[1] = w0.y; wv[2] = w0.z; wv[3] = w0.w;
            wv[4] = w1.x; wv[5] = w1.y; wv[6] = w1.z; wv[7] = w1.w;
#pragma unroll
            for (int i = 0; i < 8; ++i)
#pragma unroll
                for (int j = 0; j < 8; ++j)
                    acc[i][j] += av[i] * wv[j];
        }
    }

    // epilogue
#pragma unroll
    for (int i = 0; i < 8; ++i) {
        const int s = s0 + tr * 8 + i;
        float y[4];
#pragma unroll
        for (int j = 0; j < 4; ++j) {
            float o = acc[i][j] + bi_o[j];
            float g = acc[i][j + 4] + bi_g[j];
            o = o * sc_o[j] + sh_o[j];
            g = g * sc_g[j] + sh_g[j];
            y[j] = o * (1.f / (1.f + expf(-g)));
        }
        if (resid) {
            const float4 r = *(const float4*)(A + (size_t)s * K + co);
            y[0] = (r.x + y[0]) * RES_SCALE_C;
            y[1] = (r.y + y[1]) * RES_SCALE_C;
            y[2] = (r.z + y[2]) * RES_SCALE_C;
            y[3] = (r.w + y[3]) * RES_SCALE_C;
        }
        float4 st = make_float4(y[0], y[1], y[2], y[3]);
        if (wmode == 0) {
            *(float4*)(out + (size_t)s * 128 + co) = st;
        } else {
            if (co >= 64) {
                *(float4*)(a_out + (size_t)s * 64 + (co - 64)) = st;
            } else if (wmode >= 2) {
                st.x = fmaxf(st.x, 0.f); st.y = fmaxf(st.y, 0.f);
                st.z = fmaxf(st.z, 0.f); st.w = fmaxf(st.w, 0.f);
                float* dp = dsum + (size_t)s * 64 + co;
                if (wmode == 2) {
                    *(float4*)dp = st;
                } else {
                    float4 old = *(const float4*)dp;
                    st.x += old.x; st.y += old.y; st.z += old.z; st.w += old.w;
                    *(float4*)dp = st;
                }
            }
        }
    }
}

// ---------------------------------------------------------------- attention GEMM + BN + sparsemax + prior update
// 256 threads = 16 samples x 16 threads; each thread owns 5 of the 80 groups.
__global__ __launch_bounds__(256)
void att_sparsemax_kernel(const float* __restrict__ a,
                          const float* __restrict__ att_W,   // 64x80 for this step
                          const float* __restrict__ att_b,   // 80
                          const float* __restrict__ att_bn,  // 4x80
                          float* __restrict__ prior,
                          float* __restrict__ maskg,
                          int step)
{
    __shared__ float a_lds[16 * 64];
    __shared__ float w_lds[64 * 80];
    __shared__ float z_lds[16][84];
    const int t = threadIdx.x;
    const int s0 = blockIdx.x * 16;

    ((float4*)a_lds)[t] = ((const float4*)(a + (size_t)s0 * 64))[t];
#pragma unroll
    for (int it = 0; it < 5; ++it)
        ((float4*)w_lds)[t + it * 256] = ((const float4*)att_W)[t + it * 256];
    __syncthreads();

    const int samp = t >> 4;
    const int g0 = (t & 15) * 5;
    const int s = s0 + samp;

    float dot[5];
#pragma unroll
    for (int j = 0; j < 5; ++j) dot[j] = att_b[g0 + j];
    for (int k = 0; k < 64; ++k) {
        const float av = a_lds[samp * 64 + k];
#pragma unroll
        for (int j = 0; j < 5; ++j)
            dot[j] += av * w_lds[k * 80 + g0 + j];
    }

    float z[5], pr[5];
#pragma unroll
    for (int j = 0; j < 5; ++j) {
        const int g = g0 + j;
        const float sc = att_bn[g] / sqrtf(att_bn[240 + g] + BN_EPS_C);
        const float bnv = (dot[j] - att_bn[160 + g]) * sc + att_bn[80 + g];
        pr[j] = (step == 0) ? 1.f : prior[(size_t)s * 80 + g];
        z[j] = bnv * pr[j];
        z_lds[samp][g] = z[j];
    }
    __syncthreads();

    // sparsemax via all-pairs rank stats: c_j = #{z_i >= z_j}, S_j = sum{z_i >= z_j}
    float cj[5] = {0, 0, 0, 0, 0}, Sj[5] = {0, 0, 0, 0, 0};
    for (int i = 0; i < 80; ++i) {
        const float zi = z_lds[samp][i];
#pragma unroll
        for (int j = 0; j < 5; ++j) {
            if (zi >= z[j]) { cj[j] += 1.f; Sj[j] += zi; }
        }
    }
    float cnt = 0.f, csum = 0.f;
#pragma unroll
    for (int j = 0; j < 5; ++j) {
        const bool in_sup = (1.f + cj[j] * z[j]) > Sj[j];
        if (in_sup) { cnt += 1.f; csum += z[j]; }
    }
#pragma unroll
    for (int m = 1; m < 16; m <<= 1) {
        cnt += __shfl_xor(cnt, m);
        csum += __shfl_xor(csum, m);
    }
    const float tau = (csum - 1.f) / cnt;
#pragma unroll
    for (int j = 0; j < 5; ++j) {
        const int g = g0 + j;
        const float mk = fmaxf(z[j] - tau, 0.f);
        maskg[(size_t)s * 80 + g] = mk;
        prior[(size_t)s * 80 + g] = pr[j] * (GAMMA_C - mk);
    }
}

// ---------------------------------------------------------------- final 64 -> 1
__global__ void final_kernel(const float* __restrict__ dsum,
                             const float* __restrict__ out_W,
                             const float* __restrict__ out_b,
                             float* __restrict__ out)
{
    const int s = blockIdx.x * 256 + threadIdx.x;
    float acc = out_b[0];
    const float4* dp = (const float4*)(dsum + (size_t)s * 64);
    const float4* wp = (const float4*)out_W;
#pragma unroll
    for (int q = 0; q < 16; ++q) {
        const float4 d = dp[q];
        const float4 w = wp[q];
        acc += d.x * w.x + d.y * w.y + d.z * w.z + d.w * w.w;
    }
    out[s] = acc;
}

// ---------------------------------------------------------------- launch
extern "C" void kernel_launch(void* const* d_in, const int* in_sizes, int n_in,
                              void* d_out, int out_size, void* d_ws, size_t ws_size,
                              hipStream_t stream)
{
    const float* x_num  = (const float*)d_in[0];
    const int*   x_cat  = (const int*)d_in[1];
    const float* emb_W  = (const float*)d_in[2];
    const float* in_bn  = (const float*)d_in[3];
    const float* sh_W0  = (const float*)d_in[4];
    const float* sh_b0  = (const float*)d_in[5];
    const float* sh_bn0 = (const float*)d_in[6];
    const float* sh_W1  = (const float*)d_in[7];
    const float* sh_b1  = (const float*)d_in[8];
    const float* sh_bn1 = (const float*)d_in[9];
    const float* init_W = (const float*)d_in[10];
    const float* init_b = (const float*)d_in[11];
    const float* init_bn= (const float*)d_in[12];
    const float* step_W = (const float*)d_in[13];
    const float* step_b = (const float*)d_in[14];
    const float* step_bn= (const float*)d_in[15];
    const float* att_W  = (const float*)d_in[16];
    const float* att_b  = (const float*)d_in[17];
    const float* att_bn = (const float*)d_in[18];
    const float* out_W  = (const float*)d_in[19];
    const float* out_b  = (const float*)d_in[20];

    const int B = 65536;
    float* ws  = (float*)d_ws;
    float* x   = ws;                         // B*320
    float* hA  = x  + (size_t)B * 320;       // B*128
    float* hB  = hA + (size_t)B * 128;       // B*128
    float* av  = hB + (size_t)B * 128;       // B*64
    float* pri = av + (size_t)B * 64;        // B*80
    float* mg  = pri + (size_t)B * 80;       // B*80
    float* ds  = mg + (size_t)B * 80;        // B*64

    embed_bn_kernel<<<B, 320, 0, stream>>>(x_num, x_cat, emb_W, in_bn, x);

    const int GB = B / 64;
    // init pass: shared(2) + indep(2); last layer emits a only
    glu_gemm<320, false><<<GB, 256, 0, stream>>>(x,  nullptr, sh_W0, sh_b0, sh_bn0, hA, nullptr, nullptr, 0, 0);
    glu_gemm<128, false><<<GB, 256, 0, stream>>>(hA, nullptr, sh_W1, sh_b1, sh_bn1, hB, nullptr, nullptr, 1, 0);
    glu_gemm<128, false><<<GB, 256, 0, stream>>>(hB, nullptr, init_W,              init_b,       init_bn,        hA, nullptr, nullptr, 1, 0);
    glu_gemm<128, false><<<GB, 256, 0, stream>>>(hA, nullptr, init_W + 128 * 256,  init_b + 256, init_bn + 1024, nullptr, av, nullptr, 1, 1);

    for (int st = 0; st < 5; ++st) {
        att_sparsemax_kernel<<<B / 16, 256, 0, stream>>>(av, att_W + st * 64 * 80, att_b + st * 80,
                                                         att_bn + st * 4 * 80, pri, mg, st);
        glu_gemm<320, true ><<<GB, 256, 0, stream>>>(x,  mg,      sh_W0, sh_b0, sh_bn0, hA, nullptr, nullptr, 0, 0);
        glu_gemm<128, false><<<GB, 256, 0, stream>>>(hA, nullptr, sh_W1, sh_b1, sh_bn1, hB, nullptr, nullptr, 1, 0);
        const float* W0 = step_W + (size_t)(st * 2 + 0) * 128 * 256;
        const float* W1 = step_W + (size_t)(st * 2 + 1) * 128 * 256;
        glu_gemm<128, false><<<GB, 256, 0, stream>>>(hB, nullptr, W0, step_b + (st * 2 + 0) * 256,
                                                     step_bn + (st * 2 + 0) * 1024, hA, nullptr, nullptr, 1, 0);
        glu_gemm<128, false><<<GB, 256, 0, stream>>>(hA, nullptr, W1, step_b + (st * 2 + 1) * 256,
                                                     step_bn + (st * 2 + 1) * 1024, nullptr, av, ds, 1, st == 0 ? 2 : 3);
    }
    final_kernel<<<B / 256, 256, 0, stream>>>(ds, out_W, out_b, (float*)d_out);
}

// Round 2
// 2158.229 us; speedup vs baseline: 1.3681x; 1.3681x over previous
//
#include <hip/hip_runtime.h>
#include <math.h>

typedef _Float16 half_t;
typedef _Float16 half8 __attribute__((ext_vector_type(8)));
typedef float floatx4 __attribute__((ext_vector_type(4)));

constexpr float BN_EPS_C = 1e-5f;
constexpr float RES_SCALE_C = 0.70710678118654752f;
constexpr float GAMMA_C = 1.5f;
#define B_TOT 65536

// ---------------------------------------------------------------- W split+repack (once per launch)
// Fragment-major: element (k,n) -> [( (k>>3)*256 + n )*8 + (k&7)], hi and lo planes.
// Rows (k) of all GEMM weight matrices concatenated: 320 + 128 + 2*128 + 10*128 = 1984 blocks.
__global__ void wsplit_kernel(const float* __restrict__ sh_W0, const float* __restrict__ sh_W1,
                              const float* __restrict__ init_W, const float* __restrict__ step_W,
                              half_t* __restrict__ Wh, half_t* __restrict__ Wl)
{
    const int b = blockIdx.x, n = threadIdx.x;
    const float* src; int k; size_t base;
    if (b < 320)      { src = sh_W0;           k = b;       base = 0; }
    else if (b < 448) { src = sh_W1;           k = b - 320; base = 81920; }
    else if (b < 576) { src = init_W;          k = b - 448; base = 114688; }
    else if (b < 704) { src = init_W + 32768;  k = b - 576; base = 147456; }
    else {
        int j = (b - 704) >> 7; k = (b - 704) & 127;
        src = step_W + (size_t)j * 32768; base = 180224 + (size_t)j * 32768;
    }
    const float v = src[k * 256 + n];
    const half_t hi = (half_t)v;
    const half_t lo = (half_t)(v - (float)hi);
    const size_t idx = base + (size_t)(((k >> 3) * 256 + n) * 8 + (k & 7));
    Wh[idx] = hi; Wl[idx] = lo;
}

// ---------------------------------------------------------------- embed + input BN -> split fp16 planes
__global__ void embed_bn_kernel(const float* __restrict__ x_num,
                                const int* __restrict__ x_cat,
                                const float* __restrict__ emb_W,
                                const float* __restrict__ in_bn,
                                half_t* __restrict__ xh, half_t* __restrict__ xl)
{
    const int s = blockIdx.x;
    const int j = threadIdx.x;   // 0..319
    float v;
    if (j < 64) {
        v = x_num[(size_t)s * 64 + j];
    } else {
        const int c = (j - 64) >> 4, e = (j - 64) & 15;
        const int idx = x_cat[(size_t)s * 16 + c];
        v = emb_W[(size_t)(c * 1000 + idx) * 16 + e];
    }
    const float sc = in_bn[j], bb = in_bn[320 + j], mm = in_bn[640 + j], vv = in_bn[960 + j];
    const float val = (v - mm) * (sc / sqrtf(vv + BN_EPS_C)) + bb;
    const half_t h = (half_t)val;
    xh[(size_t)s * 320 + j] = h;
    xl[(size_t)s * 320 + j] = (half_t)(val - (float)h);
}

// ---------------------------------------------------------------- split-fp16 MFMA GEMM + BN + GLU
// Block: 64 samples x 256 cols, 4 waves. Wave w owns col tiles {2w,2w+1} (o) and {2w+8,2w+9} (g)
// so each o-channel pairs with its gate in-wave. 3 MFMA products per tile (drop AlBl).
// wmode: 0 = write split Oh/Ol (128 cols); 1 = av only; 2 = av + ds=relu(d); 3 = av + ds+=relu(d)
template<int K, bool MASK>
__global__ __launch_bounds__(256, 3)
void glu_gemm_mfma(const half_t* __restrict__ Ah_g, const half_t* __restrict__ Al_g,
                   const float* __restrict__ mg,
                   const half_t* __restrict__ Wh, const half_t* __restrict__ Wl,
                   const float* __restrict__ bias, const float* __restrict__ bn,
                   half_t* __restrict__ Oh, half_t* __restrict__ Ol,
                   float* __restrict__ av, float* __restrict__ ds,
                   const half_t* __restrict__ Rh, const half_t* __restrict__ Rl,
                   int wmode)
{
    __shared__ half_t As_h[64][40];   // +8 halves pad: frag reads are 2-way (free) on banks
    __shared__ half_t As_l[64][40];
    const int t = threadIdx.x;
    const int s0 = blockIdx.x * 64;
    const int w = t >> 6, lane = t & 63, quad = lane >> 4, l16 = lane & 15;

    floatx4 acc[4][4];
#pragma unroll
    for (int i = 0; i < 4; ++i)
#pragma unroll
        for (int j = 0; j < 4; ++j) acc[i][j] = (floatx4){0.f, 0.f, 0.f, 0.f};

    int cb[4];
    cb[0] = (2 * w) * 16; cb[1] = (2 * w + 1) * 16;
    cb[2] = 128 + cb[0];  cb[3] = 128 + cb[1];

    const int s_a = t >> 2, q_a = t & 3;
    const half_t* arow_h = Ah_g + (size_t)(s0 + s_a) * K + q_a * 8;
    const half_t* arow_l = Al_g + (size_t)(s0 + s_a) * K + q_a * 8;
    const float* mrow = MASK ? (mg + (size_t)(s0 + s_a) * 80) : nullptr;

    for (int kc = 0; kc < K; kc += 32) {
        __syncthreads();
        half8 ah = *(const half8*)(arow_h + kc);
        half8 al = *(const half8*)(arow_l + kc);
        if (MASK) {
#pragma unroll
            for (int j = 0; j < 8; ++j) {
                const int k = kc + q_a * 8 + j;
                const int g = (k < 64) ? k : (64 + ((k - 64) >> 4));
                const float v = ((float)ah[j] + (float)al[j]) * mrow[g];
                const half_t h = (half_t)v;
                ah[j] = h; al[j] = (half_t)(v - (float)h);
            }
        }
        *(half8*)&As_h[s_a][q_a * 8] = ah;
        *(half8*)&As_l[s_a][q_a * 8] = al;
        __syncthreads();

        half8 a_h[4], a_l[4];
#pragma unroll
        for (int mt = 0; mt < 4; ++mt) {
            a_h[mt] = *(const half8*)&As_h[mt * 16 + l16][quad * 8];
            a_l[mt] = *(const half8*)&As_l[mt * 16 + l16][quad * 8];
        }
        const int kq = (kc >> 3) + quad;
#pragma unroll
        for (int nt = 0; nt < 4; ++nt) {
            const size_t wi = (size_t)(kq * 256 + cb[nt] + l16) * 8;
            const half8 b_h = *(const half8*)(Wh + wi);
            const half8 b_l = *(const half8*)(Wl + wi);
#pragma unroll
            for (int mt = 0; mt < 4; ++mt) {
                acc[mt][nt] = __builtin_amdgcn_mfma_f32_16x16x32_f16(a_h[mt], b_h, acc[mt][nt], 0, 0, 0);
                acc[mt][nt] = __builtin_amdgcn_mfma_f32_16x16x32_f16(a_l[mt], b_h, acc[mt][nt], 0, 0, 0);
                acc[mt][nt] = __builtin_amdgcn_mfma_f32_16x16x32_f16(a_h[mt], b_l, acc[mt][nt], 0, 0, 0);
            }
        }
    }

    // epilogue: o-tile j pairs with g-tile j+2; C/D layout: row = quad*4+reg, col = l16
#pragma unroll
    for (int j = 0; j < 2; ++j) {
        const int c = cb[j] + l16;          // o channel, in [0,128)
        const int c2 = c + 128;             // gate channel
        const float sc_o = bn[c]  / sqrtf(bn[768 + c]  + BN_EPS_C);
        const float sh_o = bn[256 + c]  - bn[512 + c]  * sc_o;
        const float sc_g = bn[c2] / sqrtf(bn[768 + c2] + BN_EPS_C);
        const float sh_g = bn[256 + c2] - bn[512 + c2] * sc_g;
        const float bi_o = bias[c], bi_g = bias[c2];
#pragma unroll
        for (int mt = 0; mt < 4; ++mt) {
#pragma unroll
            for (int r = 0; r < 4; ++r) {
                const int s = s0 + mt * 16 + quad * 4 + r;
                float o = acc[mt][j][r] + bi_o;
                float g = acc[mt][j + 2][r] + bi_g;
                o = o * sc_o + sh_o;
                g = g * sc_g + sh_g;
                float y = o * (1.f / (1.f + expf(-g)));
                if (Rh) {
                    y = (y + (float)Rh[(size_t)s * K + c] + (float)Rl[(size_t)s * K + c]) * RES_SCALE_C;
                }
                if (wmode == 0) {
                    const half_t h = (half_t)y;
                    Oh[(size_t)s * 128 + c] = h;
                    Ol[(size_t)s * 128 + c] = (half_t)(y - (float)h);
                } else {
                    if (c < 64) {
                        if (wmode >= 2) {
                            const float d = fmaxf(y, 0.f);
                            float* dp = ds + (size_t)s * 64 + c;
                            *dp = (wmode == 2) ? d : (*dp + d);
                        }
                    } else {
                        av[(size_t)s * 64 + (c - 64)] = y;
                    }
                }
            }
        }
    }
}

// ---------------------------------------------------------------- attention GEMM + BN + sparsemax + prior
__global__ __launch_bounds__(256)
void att_sparsemax_kernel(const float* __restrict__ a,
                          const float* __restrict__ att_W,
                          const float* __restrict__ att_b,
                          const float* __restrict__ att_bn,
                          float* __restrict__ prior,
                          float* __restrict__ maskg,
                          int step)
{
    __shared__ float a_lds[16 * 64];
    __shared__ float w_lds[64 * 80];
    __shared__ float z_lds[16][84];
    const int t = threadIdx.x;
    const int s0 = blockIdx.x * 16;

    ((float4*)a_lds)[t] = ((const float4*)(a + (size_t)s0 * 64))[t];
#pragma unroll
    for (int it = 0; it < 5; ++it)
        ((float4*)w_lds)[t + it * 256] = ((const float4*)att_W)[t + it * 256];
    __syncthreads();

    const int samp = t >> 4;
    const int g0 = (t & 15) * 5;
    const int s = s0 + samp;

    float dot[5];
#pragma unroll
    for (int j = 0; j < 5; ++j) dot[j] = att_b[g0 + j];
    for (int k = 0; k < 64; ++k) {
        const float avv = a_lds[samp * 64 + k];
#pragma unroll
        for (int j = 0; j < 5; ++j)
            dot[j] += avv * w_lds[k * 80 + g0 + j];
    }

    float z[5], pr[5];
#pragma unroll
    for (int j = 0; j < 5; ++j) {
        const int g = g0 + j;
        const float sc = att_bn[g] / sqrtf(att_bn[240 + g] + BN_EPS_C);
        const float bnv = (dot[j] - att_bn[160 + g]) * sc + att_bn[80 + g];
        pr[j] = (step == 0) ? 1.f : prior[(size_t)s * 80 + g];
        z[j] = bnv * pr[j];
        z_lds[samp][g] = z[j];
    }
    __syncthreads();

    float cj[5] = {0, 0, 0, 0, 0}, Sj[5] = {0, 0, 0, 0, 0};
    for (int i = 0; i < 80; ++i) {
        const float zi = z_lds[samp][i];
#pragma unroll
        for (int j = 0; j < 5; ++j) {
            if (zi >= z[j]) { cj[j] += 1.f; Sj[j] += zi; }
        }
    }
    float cnt = 0.f, csum = 0.f;
#pragma unroll
    for (int j = 0; j < 5; ++j) {
        if ((1.f + cj[j] * z[j]) > Sj[j]) { cnt += 1.f; csum += z[j]; }
    }
#pragma unroll
    for (int m = 1; m < 16; m <<= 1) {
        cnt += __shfl_xor(cnt, m);
        csum += __shfl_xor(csum, m);
    }
    const float tau = (csum - 1.f) / cnt;
#pragma unroll
    for (int j = 0; j < 5; ++j) {
        const int g = g0 + j;
        const float mk = fmaxf(z[j] - tau, 0.f);
        maskg[(size_t)s * 80 + g] = mk;
        prior[(size_t)s * 80 + g] = pr[j] * (GAMMA_C - mk);
    }
}

// ---------------------------------------------------------------- final 64 -> 1
__global__ void final_kernel(const float* __restrict__ dsum,
                             const float* __restrict__ out_W,
                             const float* __restrict__ out_b,
                             float* __restrict__ out)
{
    const int s = blockIdx.x * 256 + threadIdx.x;
    float acc = out_b[0];
    const float4* dp = (const float4*)(dsum + (size_t)s * 64);
    const float4* wp = (const float4*)out_W;
#pragma unroll
    for (int q = 0; q < 16; ++q) {
        const float4 d = dp[q];
        const float4 ww = wp[q];
        acc += d.x * ww.x + d.y * ww.y + d.z * ww.z + d.w * ww.w;
    }
    out[s] = acc;
}

// ---------------------------------------------------------------- launch
extern "C" void kernel_launch(void* const* d_in, const int* in_sizes, int n_in,
                              void* d_out, int out_size, void* d_ws, size_t ws_size,
                              hipStream_t stream)
{
    const float* x_num  = (const float*)d_in[0];
    const int*   x_cat  = (const int*)d_in[1];
    const float* emb_W  = (const float*)d_in[2];
    const float* in_bn  = (const float*)d_in[3];
    const float* sh_W0  = (const float*)d_in[4];
    const float* sh_b0  = (const float*)d_in[5];
    const float* sh_bn0 = (const float*)d_in[6];
    const float* sh_W1  = (const float*)d_in[7];
    const float* sh_b1  = (const float*)d_in[8];
    const float* sh_bn1 = (const float*)d_in[9];
    const float* init_W = (const float*)d_in[10];
    const float* init_b = (const float*)d_in[11];
    const float* init_bn= (const float*)d_in[12];
    const float* step_W = (const float*)d_in[13];
    const float* step_b = (const float*)d_in[14];
    const float* step_bn= (const float*)d_in[15];
    const float* att_W  = (const float*)d_in[16];
    const float* att_b  = (const float*)d_in[17];
    const float* att_bn = (const float*)d_in[18];
    const float* out_W  = (const float*)d_in[19];
    const float* out_b  = (const float*)d_in[20];

    const size_t B = B_TOT;
    half_t* xh  = (half_t*)d_ws;            // B*320
    half_t* xl  = xh  + B * 320;
    half_t* hAh = xl  + B * 320;            // B*128
    half_t* hAl = hAh + B * 128;
    half_t* hBh = hAl + B * 128;
    half_t* hBl = hBh + B * 128;
    half_t* Wh  = hBl + B * 128;            // 507904 each plane
    half_t* Wl  = Wh + 507904;
    float*  av  = (float*)(Wl + 507904);    // B*64   (16B-aligned)
    float*  pri = av  + B * 64;             // B*80
    float*  mg  = pri + B * 80;             // B*80
    float*  ds  = mg  + B * 80;             // B*64

    wsplit_kernel<<<1984, 256, 0, stream>>>(sh_W0, sh_W1, init_W, step_W, Wh, Wl);
    embed_bn_kernel<<<B_TOT, 320, 0, stream>>>(x_num, x_cat, emb_W, in_bn, xh, xl);

    const int GB = B_TOT / 64;
    // W plane offsets (halves): sh_W0=0, sh_W1=81920, init0=114688, init1=147456, step j=180224+j*32768
    glu_gemm_mfma<320, false><<<GB, 256, 0, stream>>>(xh, xl, nullptr, Wh, Wl, sh_b0, sh_bn0,
                                                      hAh, hAl, nullptr, nullptr, nullptr, nullptr, 0);
    glu_gemm_mfma<128, false><<<GB, 256, 0, stream>>>(hAh, hAl, nullptr, Wh + 81920, Wl + 81920, sh_b1, sh_bn1,
                                                      hBh, hBl, nullptr, nullptr, hAh, hAl, 0);
    glu_gemm_mfma<128, false><<<GB, 256, 0, stream>>>(hBh, hBl, nullptr, Wh + 114688, Wl + 114688, init_b, init_bn,
                                                      hAh, hAl, nullptr, nullptr, hBh, hBl, 0);
    glu_gemm_mfma<128, false><<<GB, 256, 0, stream>>>(hAh, hAl, nullptr, Wh + 147456, Wl + 147456, init_b + 256, init_bn + 1024,
                                                      nullptr, nullptr, av, nullptr, hAh, hAl, 1);

    for (int st = 0; st < 5; ++st) {
        att_sparsemax_kernel<<<B_TOT / 16, 256, 0, stream>>>(av, att_W + st * 5120, att_b + st * 80,
                                                             att_bn + st * 320, pri, mg, st);
        glu_gemm_mfma<320, true ><<<GB, 256, 0, stream>>>(xh, xl, mg, Wh, Wl, sh_b0, sh_bn0,
                                                          hAh, hAl, nullptr, nullptr, nullptr, nullptr, 0);
        glu_gemm_mfma<128, false><<<GB, 256, 0, stream>>>(hAh, hAl, nullptr, Wh + 81920, Wl + 81920, sh_b1, sh_bn1,
                                                          hBh, hBl, nullptr, nullptr, hAh, hAl, 0);
        const size_t w0 = 180224 + (size_t)(st * 2 + 0) * 32768;
        const size_t w1 = 180224 + (size_t)(st * 2 + 1) * 32768;
        glu_gemm_mfma<128, false><<<GB, 256, 0, stream>>>(hBh, hBl, nullptr, Wh + w0, Wl + w0,
                                                          step_b + (st * 2 + 0) * 256, step_bn + (st * 2 + 0) * 1024,
                                                          hAh, hAl, nullptr, nullptr, hBh, hBl, 0);
        glu_gemm_mfma<128, false><<<GB, 256, 0, stream>>>(hAh, hAl, nullptr, Wh + w1, Wl + w1,
                                                          step_b + (st * 2 + 1) * 256, step_bn + (st * 2 + 1) * 1024,
                                                          nullptr, nullptr, av, ds, hAh, hAl, st == 0 ? 2 : 3);
    }
    final_kernel<<<B_TOT / 256, 256, 0, stream>>>(ds, out_W, out_b, (float*)d_out);
}

// Round 3
// 1282.030 us; speedup vs baseline: 2.3032x; 1.6834x over previous
//
#include <hip/hip_runtime.h>
#include <math.h>
#include <stdint.h>

typedef _Float16 half_t;
typedef _Float16 half8 __attribute__((ext_vector_type(8)));
typedef float floatx4 __attribute__((ext_vector_type(4)));

constexpr float BN_EPS_C = 1e-5f;
constexpr float RES_SCALE_C = 0.70710678118654752f;
constexpr float GAMMA_C = 1.5f;
#define B_TOT 65536

// ---------------- packed (hi,lo) fp16-pair helpers: word = hi | lo<<16 ----------------
__device__ __forceinline__ uint32_t pack2(float y) {
    const half_t h = (half_t)y;
    const half_t l = (half_t)(y - (float)h);
    union { half_t f; unsigned short u; } a, b; a.f = h; b.f = l;
    return (uint32_t)a.u | ((uint32_t)b.u << 16);
}
__device__ __forceinline__ void unpack2(uint32_t v, half_t& h, half_t& l) {
    union { unsigned short u; half_t f; } a, b;
    a.u = (unsigned short)(v & 0xffffu); b.u = (unsigned short)(v >> 16);
    h = a.f; l = b.f;
}
__device__ __forceinline__ float upksum(uint32_t v) {
    half_t h, l; unpack2(v, h, l); return (float)h + (float)l;
}
__device__ __forceinline__ void unpack8(const uint32_t* wv, half8& h, half8& l) {
#pragma unroll
    for (int j = 0; j < 8; ++j) {
        half_t hh, ll; unpack2(wv[j], hh, ll);
        h[j] = hh; l[j] = ll;
    }
}

// ---------------- W split+repack (fragment-major, hi/lo planes) ----------------
// element (k,n) -> [((k>>3)*256 + n)*8 + (k&7)]; row blocks: 320+128+128+128+10*128 = 1984
__global__ void wsplit_kernel(const float* __restrict__ sh_W0, const float* __restrict__ sh_W1,
                              const float* __restrict__ init_W, const float* __restrict__ step_W,
                              half_t* __restrict__ Wh, half_t* __restrict__ Wl)
{
    const int b = blockIdx.x, n = threadIdx.x;
    const float* src; int k; size_t base;
    if (b < 320)      { src = sh_W0;           k = b;       base = 0; }
    else if (b < 448) { src = sh_W1;           k = b - 320; base = 81920; }
    else if (b < 576) { src = init_W;          k = b - 448; base = 114688; }
    else if (b < 704) { src = init_W + 32768;  k = b - 576; base = 147456; }
    else {
        int j = (b - 704) >> 7; k = (b - 704) & 127;
        src = step_W + (size_t)j * 32768; base = 180224 + (size_t)j * 32768;
    }
    const float v = src[k * 256 + n];
    const half_t hi = (half_t)v;
    const half_t lo = (half_t)(v - (float)hi);
    const size_t idx = base + (size_t)(((k >> 3) * 256 + n) * 8 + (k & 7));
    Wh[idx] = hi; Wl[idx] = lo;
}

// attention weights: per step, (k,n) n<80 -> step*5120 + ((k>>3)*80 + n)*8 + (k&7)
__global__ void wsplit_att_kernel(const float* __restrict__ att_W,
                                  half_t* __restrict__ aWh, half_t* __restrict__ aWl)
{
    const int b = blockIdx.x;        // step*64 + k
    const int n = threadIdx.x;       // 0..79
    const int step = b >> 6, k = b & 63;
    const float v = att_W[(size_t)b * 80 + n];
    const half_t h = (half_t)v;
    const half_t l = (half_t)(v - (float)h);
    const size_t idx = (size_t)step * 5120 + (size_t)(((k >> 3) * 80 + n) * 8 + (k & 7));
    aWh[idx] = h; aWl[idx] = l;
}

// ---------------- embed + input BN -> packed x ----------------
__global__ void embed_bn_kernel(const float* __restrict__ x_num, const int* __restrict__ x_cat,
                                const float* __restrict__ emb_W, const float* __restrict__ in_bn,
                                uint32_t* __restrict__ xp)
{
    const int idx = blockIdx.x * 256 + threadIdx.x;   // < B*320
    const int s = idx / 320, j = idx - s * 320;
    float v;
    if (j < 64) v = x_num[(size_t)s * 64 + j];
    else {
        const int c = (j - 64) >> 4, e = (j - 64) & 15;
        v = emb_W[(size_t)(c * 1000 + x_cat[(size_t)s * 16 + c]) * 16 + e];
    }
    const float val = (v - in_bn[640 + j]) * (in_bn[j] / sqrtf(in_bn[960 + j] + BN_EPS_C)) + in_bn[320 + j];
    xp[idx] = pack2(val);
}

// ---------------- fused FT chain: L1(K=320, from global x[*mask]) -> L2 -> L3 -> L4 ----------------
// 64 samples/block, 256 threads (4 waves). h kept in LDS packed between layers.
// wmode_last: 1 = av only; 2 = av + ds=relu(d); 3 = av + ds+=relu(d)

__device__ __forceinline__ void lds_layer_mfma(const uint32_t (*h_lds)[132],
                                               const half_t* __restrict__ Wh,
                                               const half_t* __restrict__ Wl,
                                               size_t off, int l16, int quad, const int* cb,
                                               floatx4 acc[4][4])
{
#pragma unroll
    for (int kc = 0; kc < 128; kc += 32) {
        half8 a_h[4], a_l[4];
#pragma unroll
        for (int mt = 0; mt < 4; ++mt) {
            uint32_t wv[8];
            *(uint4*)&wv[0] = *(const uint4*)&h_lds[mt * 16 + l16][kc + quad * 8];
            *(uint4*)&wv[4] = *(const uint4*)&h_lds[mt * 16 + l16][kc + quad * 8 + 4];
            unpack8(wv, a_h[mt], a_l[mt]);
        }
        const int kq = (kc >> 3) + quad;
#pragma unroll
        for (int nt = 0; nt < 4; ++nt) {
            const size_t wi = off + (size_t)(kq * 256 + cb[nt] + l16) * 8;
            const half8 b_h = *(const half8*)(Wh + wi);
            const half8 b_l = *(const half8*)(Wl + wi);
#pragma unroll
            for (int mt = 0; mt < 4; ++mt)
                acc[mt][nt] = __builtin_amdgcn_mfma_f32_16x16x32_f16(a_h[mt], b_h, acc[mt][nt], 0, 0, 0);
#pragma unroll
            for (int mt = 0; mt < 4; ++mt)
                acc[mt][nt] = __builtin_amdgcn_mfma_f32_16x16x32_f16(a_l[mt], b_h, acc[mt][nt], 0, 0, 0);
#pragma unroll
            for (int mt = 0; mt < 4; ++mt)
                acc[mt][nt] = __builtin_amdgcn_mfma_f32_16x16x32_f16(a_h[mt], b_l, acc[mt][nt], 0, 0, 0);
        }
    }
}

template<bool MASK>
__global__ __launch_bounds__(256, 3)
void ft_chain(const uint32_t* __restrict__ xp, const float* __restrict__ mg,
              const half_t* __restrict__ Wh, const half_t* __restrict__ Wl,
              const float* __restrict__ b1, const float* __restrict__ bn1,
              const float* __restrict__ b2, const float* __restrict__ bn2,
              const float* __restrict__ b3, const float* __restrict__ bn3,
              const float* __restrict__ b4, const float* __restrict__ bn4,
              size_t w3_off, size_t w4_off,
              uint32_t* __restrict__ avp, float* __restrict__ ds, int wmode_last)
{
    __shared__ half_t As_h[64][40];
    __shared__ half_t As_l[64][40];
    __shared__ uint32_t h_lds[64][132];   // packed hi|lo, +4 word pad
    const int t = threadIdx.x;
    const int s0 = blockIdx.x * 64;
    const int w = t >> 6, lane = t & 63, quad = lane >> 4, l16 = lane & 15;
    int cb[4];
    cb[0] = 32 * w; cb[1] = 32 * w + 16; cb[2] = 128 + cb[0]; cb[3] = 128 + cb[1];

    // ------------- L1: K=320, A from global packed x (masked for step passes)
    floatx4 acc[4][4];
#pragma unroll
    for (int i = 0; i < 4; ++i)
#pragma unroll
        for (int j = 0; j < 4; ++j) acc[i][j] = (floatx4){0.f, 0.f, 0.f, 0.f};

    const int row_a = t >> 2, k0_a = (t & 3) * 8;
    const uint32_t* arow = xp + (size_t)(s0 + row_a) * 320;
    const float* mrow = MASK ? (mg + (size_t)(s0 + row_a) * 80) : nullptr;

    for (int kc = 0; kc < 320; kc += 32) {
        __syncthreads();
        const int kb = kc + k0_a;
        uint32_t wv[8];
        *(uint4*)&wv[0] = *(const uint4*)(arow + kb);
        *(uint4*)&wv[4] = *(const uint4*)(arow + kb + 4);
        half8 hh, ll;
        if (MASK) {
            if (kb >= 64) {
                const float m = mrow[64 + ((kb - 64) >> 4)];
#pragma unroll
                for (int j = 0; j < 8; ++j) {
                    half_t h, l; unpack2(wv[j], h, l);
                    const float v = ((float)h + (float)l) * m;
                    const half_t nh = (half_t)v;
                    hh[j] = nh; ll[j] = (half_t)(v - (float)nh);
                }
            } else {
#pragma unroll
                for (int j = 0; j < 8; ++j) {
                    half_t h, l; unpack2(wv[j], h, l);
                    const float v = ((float)h + (float)l) * mrow[kb + j];
                    const half_t nh = (half_t)v;
                    hh[j] = nh; ll[j] = (half_t)(v - (float)nh);
                }
            }
        } else {
#pragma unroll
            for (int j = 0; j < 8; ++j) { half_t h, l; unpack2(wv[j], h, l); hh[j] = h; ll[j] = l; }
        }
        *(half8*)&As_h[row_a][k0_a] = hh;
        *(half8*)&As_l[row_a][k0_a] = ll;
        __syncthreads();

        half8 a_h[4], a_l[4];
#pragma unroll
        for (int mt = 0; mt < 4; ++mt) {
            a_h[mt] = *(const half8*)&As_h[mt * 16 + l16][quad * 8];
            a_l[mt] = *(const half8*)&As_l[mt * 16 + l16][quad * 8];
        }
        const int kq = (kc >> 3) + quad;
#pragma unroll
        for (int nt = 0; nt < 4; ++nt) {
            const size_t wi = (size_t)(kq * 256 + cb[nt] + l16) * 8;
            const half8 b_h = *(const half8*)(Wh + wi);
            const half8 b_l = *(const half8*)(Wl + wi);
#pragma unroll
            for (int mt = 0; mt < 4; ++mt)
                acc[mt][nt] = __builtin_amdgcn_mfma_f32_16x16x32_f16(a_h[mt], b_h, acc[mt][nt], 0, 0, 0);
#pragma unroll
            for (int mt = 0; mt < 4; ++mt)
                acc[mt][nt] = __builtin_amdgcn_mfma_f32_16x16x32_f16(a_l[mt], b_h, acc[mt][nt], 0, 0, 0);
#pragma unroll
            for (int mt = 0; mt < 4; ++mt)
                acc[mt][nt] = __builtin_amdgcn_mfma_f32_16x16x32_f16(a_h[mt], b_l, acc[mt][nt], 0, 0, 0);
        }
    }

    // L1 epilogue -> h_lds (no residual)
#pragma unroll
    for (int j = 0; j < 2; ++j) {
        const int c = cb[j] + l16, c2 = c + 128;
        const float sc_o = bn1[c] / sqrtf(bn1[768 + c] + BN_EPS_C);
        const float sh_o = bn1[256 + c] - bn1[512 + c] * sc_o;
        const float sc_g = bn1[c2] / sqrtf(bn1[768 + c2] + BN_EPS_C);
        const float sh_g = bn1[256 + c2] - bn1[512 + c2] * sc_g;
        const float bi_o = b1[c], bi_g = b1[c2];
#pragma unroll
        for (int mt = 0; mt < 4; ++mt)
#pragma unroll
            for (int r = 0; r < 4; ++r) {
                const int sl = mt * 16 + quad * 4 + r;
                const float o = (acc[mt][j][r] + bi_o) * sc_o + sh_o;
                const float g = (acc[mt][j + 2][r] + bi_g) * sc_g + sh_g;
                const float y = o / (1.f + __expf(-g));
                h_lds[sl][c] = pack2(y);
            }
    }
    __syncthreads();

    // ------------- L2, L3: K=128 from LDS, residual, back to LDS
    const float* bia[2] = { b2, b3 };
    const float* bns[2] = { bn2, bn3 };
    const size_t offs[2] = { (size_t)81920, w3_off };
#pragma unroll 1
    for (int layer = 0; layer < 2; ++layer) {
#pragma unroll
        for (int i = 0; i < 4; ++i)
#pragma unroll
            for (int j = 0; j < 4; ++j) acc[i][j] = (floatx4){0.f, 0.f, 0.f, 0.f};
        lds_layer_mfma(h_lds, Wh, Wl, offs[layer], l16, quad, cb, acc);
        __syncthreads();
        const float* bb = bia[layer];
        const float* bn = bns[layer];
#pragma unroll
        for (int j = 0; j < 2; ++j) {
            const int c = cb[j] + l16, c2 = c + 128;
            const float sc_o = bn[c] / sqrtf(bn[768 + c] + BN_EPS_C);
            const float sh_o = bn[256 + c] - bn[512 + c] * sc_o;
            const float sc_g = bn[c2] / sqrtf(bn[768 + c2] + BN_EPS_C);
            const float sh_g = bn[256 + c2] - bn[512 + c2] * sc_g;
            const float bi_o = bb[c], bi_g = bb[c2];
#pragma unroll
            for (int mt = 0; mt < 4; ++mt)
#pragma unroll
                for (int r = 0; r < 4; ++r) {
                    const int sl = mt * 16 + quad * 4 + r;
                    const float o = (acc[mt][j][r] + bi_o) * sc_o + sh_o;
                    const float g = (acc[mt][j + 2][r] + bi_g) * sc_g + sh_g;
                    const float res = upksum(h_lds[sl][c]);
                    const float y = (o / (1.f + __expf(-g)) + res) * RES_SCALE_C;
                    h_lds[sl][c] = pack2(y);
                }
        }
        __syncthreads();
    }

    // ------------- L4: K=128 from LDS, residual, outputs to global (av / ds)
#pragma unroll
    for (int i = 0; i < 4; ++i)
#pragma unroll
        for (int j = 0; j < 4; ++j) acc[i][j] = (floatx4){0.f, 0.f, 0.f, 0.f};
    lds_layer_mfma(h_lds, Wh, Wl, w4_off, l16, quad, cb, acc);
    // no barrier needed: h_lds only read from here on
#pragma unroll
    for (int j = 0; j < 2; ++j) {
        const int c = cb[j] + l16, c2 = c + 128;
        if (c < 64 && wmode_last == 1) continue;
        const float sc_o = bn4[c] / sqrtf(bn4[768 + c] + BN_EPS_C);
        const float sh_o = bn4[256 + c] - bn4[512 + c] * sc_o;
        const float sc_g = bn4[c2] / sqrtf(bn4[768 + c2] + BN_EPS_C);
        const float sh_g = bn4[256 + c2] - bn4[512 + c2] * sc_g;
        const float bi_o = b4[c], bi_g = b4[c2];
#pragma unroll
        for (int mt = 0; mt < 4; ++mt)
#pragma unroll
            for (int r = 0; r < 4; ++r) {
                const int sl = mt * 16 + quad * 4 + r;
                const int s = s0 + sl;
                const float o = (acc[mt][j][r] + bi_o) * sc_o + sh_o;
                const float g = (acc[mt][j + 2][r] + bi_g) * sc_g + sh_g;
                const float res = upksum(h_lds[sl][c]);
                const float y = (o / (1.f + __expf(-g)) + res) * RES_SCALE_C;
                if (c < 64) {
                    const float d = fmaxf(y, 0.f);
                    float* dp = ds + (size_t)s * 64 + c;
                    *dp = (wmode_last == 2) ? d : (*dp + d);
                } else {
                    avp[(size_t)s * 64 + (c - 64)] = pack2(y);
                }
            }
    }
}

// ---------------- attention: split-fp16 MFMA a@W + BN + prior + sparsemax ----------------
__global__ __launch_bounds__(256, 2)
void att_mfma_sparsemax(const uint32_t* __restrict__ avp,
                        const half_t* __restrict__ aWh, const half_t* __restrict__ aWl,
                        const float* __restrict__ att_b, const float* __restrict__ att_bn,
                        float* __restrict__ prior, float* __restrict__ maskg, int step)
{
    __shared__ half_t Ah[64][72];
    __shared__ half_t Al[64][72];
    __shared__ float z_lds[64][81];
    __shared__ float tau_lds[64];
    const int t = threadIdx.x, s0 = blockIdx.x * 64;
    const int w = t >> 6, lane = t & 63, quad = lane >> 4, l16 = lane & 15;

    {   // stage av (packed) -> split planes
        const int row = t >> 2, k0 = (t & 3) * 16;
        const uint32_t* src = avp + (size_t)(s0 + row) * 64 + k0;
        uint32_t wv[16];
        *(uint4*)&wv[0]  = *(const uint4*)(src);
        *(uint4*)&wv[4]  = *(const uint4*)(src + 4);
        *(uint4*)&wv[8]  = *(const uint4*)(src + 8);
        *(uint4*)&wv[12] = *(const uint4*)(src + 12);
        half8 h0, l0, h1, l1;
        unpack8(&wv[0], h0, l0);
        unpack8(&wv[8], h1, l1);
        *(half8*)&Ah[row][k0] = h0; *(half8*)&Ah[row][k0 + 8] = h1;
        *(half8*)&Al[row][k0] = l0; *(half8*)&Al[row][k0 + 8] = l1;
    }
    __syncthreads();

    floatx4 acc[5];
#pragma unroll
    for (int i = 0; i < 5; ++i) acc[i] = (floatx4){0.f, 0.f, 0.f, 0.f};
    const int m0 = w * 16;
#pragma unroll
    for (int kc = 0; kc < 64; kc += 32) {
        const half8 a_h = *(const half8*)&Ah[m0 + l16][kc + quad * 8];
        const half8 a_l = *(const half8*)&Al[m0 + l16][kc + quad * 8];
        const int kq = (kc >> 3) + quad;
#pragma unroll
        for (int nt = 0; nt < 5; ++nt) {
            const size_t wi = (size_t)(kq * 80 + nt * 16 + l16) * 8;
            const half8 b_h = *(const half8*)(aWh + wi);
            const half8 b_l = *(const half8*)(aWl + wi);
            acc[nt] = __builtin_amdgcn_mfma_f32_16x16x32_f16(a_h, b_h, acc[nt], 0, 0, 0);
            acc[nt] = __builtin_amdgcn_mfma_f32_16x16x32_f16(a_l, b_h, acc[nt], 0, 0, 0);
            acc[nt] = __builtin_amdgcn_mfma_f32_16x16x32_f16(a_h, b_l, acc[nt], 0, 0, 0);
        }
    }

    // BN + prior -> z (regs + LDS)
    float zreg[5][4], preg[5][4];
#pragma unroll
    for (int nt = 0; nt < 5; ++nt) {
        const int c = nt * 16 + l16;
        const float sc = att_bn[c] / sqrtf(att_bn[240 + c] + BN_EPS_C);
        const float sh = att_bn[80 + c] - att_bn[160 + c] * sc;
        const float bi = att_b[c];
#pragma unroll
        for (int r = 0; r < 4; ++r) {
            const int sl = m0 + quad * 4 + r;
            const float pr = (step == 0) ? 1.f : prior[(size_t)(s0 + sl) * 80 + c];
            const float z = ((acc[nt][r] + bi) * sc + sh) * pr;
            zreg[nt][r] = z; preg[nt][r] = pr;
            z_lds[sl][c] = z;
        }
    }
    __syncthreads();

    // sparsemax rank stats: 4 threads/sample, 20 groups each
    {
        const int sl2 = t >> 2, j0 = (t & 3) * 20;
        float zj[20], cj[20], Sj[20];
#pragma unroll
        for (int j = 0; j < 20; ++j) { zj[j] = z_lds[sl2][j0 + j]; cj[j] = 0.f; Sj[j] = 0.f; }
        for (int i = 0; i < 80; ++i) {
            const float zi = z_lds[sl2][i];
#pragma unroll
            for (int j = 0; j < 20; ++j) {
                const float ind = (zi >= zj[j]) ? 1.f : 0.f;
                cj[j] += ind;
                Sj[j] = fmaf(ind, zi, Sj[j]);
            }
        }
        float cnt = 0.f, cs = 0.f;
#pragma unroll
        for (int j = 0; j < 20; ++j)
            if (1.f + cj[j] * zj[j] > Sj[j]) { cnt += 1.f; cs += zj[j]; }
        cnt += __shfl_xor(cnt, 1); cs += __shfl_xor(cs, 1);
        cnt += __shfl_xor(cnt, 2); cs += __shfl_xor(cs, 2);
        if ((t & 3) == 0) tau_lds[sl2] = (cs - 1.f) / cnt;
    }
    __syncthreads();

    // mask + prior update
#pragma unroll
    for (int nt = 0; nt < 5; ++nt) {
        const int c = nt * 16 + l16;
#pragma unroll
        for (int r = 0; r < 4; ++r) {
            const int sl = m0 + quad * 4 + r;
            const float mk = fmaxf(zreg[nt][r] - tau_lds[sl], 0.f);
            maskg[(size_t)(s0 + sl) * 80 + c] = mk;
            prior[(size_t)(s0 + sl) * 80 + c] = preg[nt][r] * (GAMMA_C - mk);
        }
    }
}

// ---------------- final 64 -> 1 ----------------
__global__ void final_kernel(const float* __restrict__ dsum, const float* __restrict__ out_W,
                             const float* __restrict__ out_b, float* __restrict__ out)
{
    const int s = blockIdx.x * 256 + threadIdx.x;
    float acc = out_b[0];
    const float4* dp = (const float4*)(dsum + (size_t)s * 64);
    const float4* wp = (const float4*)out_W;
#pragma unroll
    for (int q = 0; q < 16; ++q) {
        const float4 d = dp[q];
        const float4 ww = wp[q];
        acc += d.x * ww.x + d.y * ww.y + d.z * ww.z + d.w * ww.w;
    }
    out[s] = acc;
}

// ---------------- launch ----------------
extern "C" void kernel_launch(void* const* d_in, const int* in_sizes, int n_in,
                              void* d_out, int out_size, void* d_ws, size_t ws_size,
                              hipStream_t stream)
{
    const float* x_num  = (const float*)d_in[0];
    const int*   x_cat  = (const int*)d_in[1];
    const float* emb_W  = (const float*)d_in[2];
    const float* in_bn  = (const float*)d_in[3];
    const float* sh_W0  = (const float*)d_in[4];
    const float* sh_b0  = (const float*)d_in[5];
    const float* sh_bn0 = (const float*)d_in[6];
    const float* sh_W1  = (const float*)d_in[7];
    const float* sh_b1  = (const float*)d_in[8];
    const float* sh_bn1 = (const float*)d_in[9];
    const float* init_W = (const float*)d_in[10];
    const float* init_b = (const float*)d_in[11];
    const float* init_bn= (const float*)d_in[12];
    const float* step_W = (const float*)d_in[13];
    const float* step_b = (const float*)d_in[14];
    const float* step_bn= (const float*)d_in[15];
    const float* att_W  = (const float*)d_in[16];
    const float* att_b  = (const float*)d_in[17];
    const float* att_bn = (const float*)d_in[18];
    const float* out_W  = (const float*)d_in[19];
    const float* out_b  = (const float*)d_in[20];

    const size_t B = B_TOT;
    char* p = (char*)d_ws;
    uint32_t* xp  = (uint32_t*)p;  p += B * 320 * 4;
    uint32_t* avp = (uint32_t*)p;  p += B * 64 * 4;
    half_t* Wh    = (half_t*)p;    p += 507904 * 2;
    half_t* Wl    = (half_t*)p;    p += 507904 * 2;
    half_t* aWh   = (half_t*)p;    p += 25600 * 2;
    half_t* aWl   = (half_t*)p;    p += 25600 * 2;
    float* pri    = (float*)p;     p += B * 80 * 4;
    float* mg     = (float*)p;     p += B * 80 * 4;
    float* ds     = (float*)p;     p += B * 64 * 4;

    wsplit_kernel<<<1984, 256, 0, stream>>>(sh_W0, sh_W1, init_W, step_W, Wh, Wl);
    wsplit_att_kernel<<<320, 80, 0, stream>>>(att_W, aWh, aWl);
    embed_bn_kernel<<<(B_TOT * 320) / 256, 256, 0, stream>>>(x_num, x_cat, emb_W, in_bn, xp);

    const int GB = B_TOT / 64;
    // init pass: sh0, sh1, init0, init1
    ft_chain<false><<<GB, 256, 0, stream>>>(xp, nullptr, Wh, Wl,
                                            sh_b0, sh_bn0, sh_b1, sh_bn1,
                                            init_b, init_bn, init_b + 256, init_bn + 1024,
                                            (size_t)114688, (size_t)147456, avp, ds, 1);
    for (int st = 0; st < 5; ++st) {
        att_mfma_sparsemax<<<GB, 256, 0, stream>>>(avp, aWh + st * 5120, aWl + st * 5120,
                                                   att_b + st * 80, att_bn + st * 320, pri, mg, st);
        const size_t w3 = 180224 + (size_t)(st * 2 + 0) * 32768;
        const size_t w4 = 180224 + (size_t)(st * 2 + 1) * 32768;
        ft_chain<true><<<GB, 256, 0, stream>>>(xp, mg, Wh, Wl,
                                               sh_b0, sh_bn0, sh_b1, sh_bn1,
                                               step_b + (st * 2 + 0) * 256, step_bn + (st * 2 + 0) * 1024,
                                               step_b + (st * 2 + 1) * 256, step_bn + (st * 2 + 1) * 1024,
                                               w3, w4, avp, ds, st == 0 ? 2 : 3);
    }
    final_kernel<<<B_TOT / 256, 256, 0, stream>>>(ds, out_W, out_b, (float*)d_out);
}

// Round 4
// 1018.912 us; speedup vs baseline: 2.8979x; 1.2582x over previous
//
#include <hip/hip_runtime.h>
#include <math.h>
#include <stdint.h>

typedef _Float16 half_t;
typedef _Float16 half8 __attribute__((ext_vector_type(8)));
typedef float floatx4 __attribute__((ext_vector_type(4)));

constexpr float BN_EPS_C = 1e-5f;
constexpr float RES_SCALE_C = 0.70710678118654752f;
constexpr float GAMMA_C = 1.5f;
#define B_TOT 65536

// ---------------- packed (hi,lo) fp16-pair helpers: word = hi | lo<<16 ----------------
__device__ __forceinline__ uint32_t pack2(float y) {
    const half_t h = (half_t)y;
    const half_t l = (half_t)(y - (float)h);
    union { half_t f; unsigned short u; } a, b; a.f = h; b.f = l;
    return (uint32_t)a.u | ((uint32_t)b.u << 16);
}
__device__ __forceinline__ void unpack2(uint32_t v, half_t& h, half_t& l) {
    union { unsigned short u; half_t f; } a, b;
    a.u = (unsigned short)(v & 0xffffu); b.u = (unsigned short)(v >> 16);
    h = a.f; l = b.f;
}

// ---------------- W split+repack (fragment-major, hi/lo planes) ----------------
// element (k,n) -> [((k>>3)*256 + n)*8 + (k&7)]; row blocks: 320+128+128+128+10*128 = 1984
__global__ void wsplit_kernel(const float* __restrict__ sh_W0, const float* __restrict__ sh_W1,
                              const float* __restrict__ init_W, const float* __restrict__ step_W,
                              half_t* __restrict__ Wh, half_t* __restrict__ Wl)
{
    const int b = blockIdx.x, n = threadIdx.x;
    const float* src; int k; size_t base;
    if (b < 320)      { src = sh_W0;           k = b;       base = 0; }
    else if (b < 448) { src = sh_W1;           k = b - 320; base = 81920; }
    else if (b < 576) { src = init_W;          k = b - 448; base = 114688; }
    else if (b < 704) { src = init_W + 32768;  k = b - 576; base = 147456; }
    else {
        int j = (b - 704) >> 7; k = (b - 704) & 127;
        src = step_W + (size_t)j * 32768; base = 180224 + (size_t)j * 32768;
    }
    const float v = src[k * 256 + n];
    const half_t hi = (half_t)v;
    const half_t lo = (half_t)(v - (float)hi);
    const size_t idx = base + (size_t)(((k >> 3) * 256 + n) * 8 + (k & 7));
    Wh[idx] = hi; Wl[idx] = lo;
}

// attention weights: per step, (k,n) n<80 -> step*5120 + ((k>>3)*80 + n)*8 + (k&7)
__global__ void wsplit_att_kernel(const float* __restrict__ att_W,
                                  half_t* __restrict__ aWh, half_t* __restrict__ aWl)
{
    const int b = blockIdx.x;        // step*64 + k
    const int n = threadIdx.x;       // 0..79
    const int step = b >> 6, k = b & 63;
    const float v = att_W[(size_t)b * 80 + n];
    const half_t h = (half_t)v;
    const half_t l = (half_t)(v - (float)h);
    const size_t idx = (size_t)step * 5120 + (size_t)(((k >> 3) * 80 + n) * 8 + (k & 7));
    aWh[idx] = h; aWl[idx] = l;
}

// ---------------- embed + input BN -> packed x ----------------
__global__ void embed_bn_kernel(const float* __restrict__ x_num, const int* __restrict__ x_cat,
                                const float* __restrict__ emb_W, const float* __restrict__ in_bn,
                                uint32_t* __restrict__ xp)
{
    const int idx = blockIdx.x * 256 + threadIdx.x;   // < B*320
    const int s = idx / 320, j = idx - s * 320;
    float v;
    if (j < 64) v = x_num[(size_t)s * 64 + j];
    else {
        const int c = (j - 64) >> 4, e = (j - 64) & 15;
        v = emb_W[(size_t)(c * 1000 + x_cat[(size_t)s * 16 + c]) * 16 + e];
    }
    const float val = (v - in_bn[640 + j]) * (in_bn[j] * __frsqrt_rn(in_bn[960 + j] + BN_EPS_C)) + in_bn[320 + j];
    xp[idx] = pack2(val);
}

// ---------------- ft_chain helpers ----------------
template<bool MASK>
__device__ __forceinline__ void stage_process(const uint32_t* pf, int kb, const float* mrow,
                                              half8& hh, half8& ll)
{
    if (MASK) {
        float m[8];
        if (kb < 64) {
            const float4 m0 = *(const float4*)(mrow + kb);
            const float4 m1 = *(const float4*)(mrow + kb + 4);
            m[0] = m0.x; m[1] = m0.y; m[2] = m0.z; m[3] = m0.w;
            m[4] = m1.x; m[5] = m1.y; m[6] = m1.z; m[7] = m1.w;
        } else {
            const float mm = mrow[64 + ((kb - 64) >> 4)];
#pragma unroll
            for (int j = 0; j < 8; ++j) m[j] = mm;
        }
#pragma unroll
        for (int j = 0; j < 8; ++j) {
            half_t h, l; unpack2(pf[j], h, l);
            const float v = ((float)h + (float)l) * m[j];
            const half_t nh = (half_t)v;
            hh[j] = nh; ll[j] = (half_t)(v - (float)nh);
        }
    } else {
#pragma unroll
        for (int j = 0; j < 8; ++j) {
            half_t h, l; unpack2(pf[j], h, l);
            hh[j] = h; ll[j] = l;
        }
    }
}

__device__ __forceinline__ void bn_fold(const float* __restrict__ bn, const float* __restrict__ bias,
                                        int c, float& sc, float& sh)
{
    sc = bn[c] * __frsqrt_rn(bn[768 + c] + BN_EPS_C);
    sh = fmaf(bias[c] - bn[512 + c], sc, bn[256 + c]);
}

__device__ __forceinline__ float glu_val(float accO, float accG,
                                         float sc_o, float sh_o, float sc_g, float sh_g)
{
    const float o = fmaf(accO, sc_o, sh_o);
    const float g = fmaf(accG, sc_g, sh_g);
    const float e = __expf(-g);
    return o * __builtin_amdgcn_rcpf(1.f + e);
}

// ---------------- fused FT chain: L1(K=320) -> L2 -> L3 -> L4, split-plane LDS ----------------
template<bool MASK>
__global__ __launch_bounds__(256, 3)
void ft_chain(const uint32_t* __restrict__ xp, const float* __restrict__ mg,
              const half_t* __restrict__ Wh, const half_t* __restrict__ Wl,
              const float* __restrict__ b1, const float* __restrict__ bn1,
              const float* __restrict__ b2, const float* __restrict__ bn2,
              const float* __restrict__ b3, const float* __restrict__ bn3,
              const float* __restrict__ b4, const float* __restrict__ bn4,
              size_t w3_off, size_t w4_off,
              uint32_t* __restrict__ avp, float* __restrict__ ds, int wmode_last)
{
    __shared__ half_t As_h[64][48];    // stride 96 B (16B-mult, bank-balanced)
    __shared__ half_t As_l[64][48];
    __shared__ half_t H_h[64][136];    // stride 272 B (16B-mult, bank-balanced)
    __shared__ half_t H_l[64][136];

    const int t = threadIdx.x;
    const int s0 = blockIdx.x * 64;
    const int w = t >> 6, lane = t & 63, quad = lane >> 4, l16 = lane & 15;
    int cb[4];
    cb[0] = 32 * w; cb[1] = 32 * w + 16; cb[2] = 128 + cb[0]; cb[3] = 128 + cb[1];

    floatx4 acc[4][4];
#pragma unroll
    for (int i = 0; i < 4; ++i)
#pragma unroll
        for (int j = 0; j < 4; ++j) acc[i][j] = (floatx4){0.f, 0.f, 0.f, 0.f};

    // ---------------- L1: K=320 from global packed x (masked), software-pipelined
    const int ra = t >> 2, ka = (t & 3) * 8;
    const uint32_t* arow = xp + (size_t)(s0 + ra) * 320 + ka;
    const float* mrow = MASK ? (mg + (size_t)(s0 + ra) * 80) : nullptr;

    uint32_t pf[8];
    *(uint4*)&pf[0] = *(const uint4*)(arow);
    *(uint4*)&pf[4] = *(const uint4*)(arow + 4);
    half8 st_h, st_l;
    stage_process<MASK>(pf, ka, mrow, st_h, st_l);

#pragma unroll 1
    for (int ic = 0; ic < 10; ++ic) {
        const int kc = ic * 32;
        __syncthreads();
        *(half8*)&As_h[ra][ka] = st_h;
        *(half8*)&As_l[ra][ka] = st_l;
        __syncthreads();
        if (ic < 9) {   // prefetch next chunk; flies during MFMA phase
            *(uint4*)&pf[0] = *(const uint4*)(arow + kc + 32);
            *(uint4*)&pf[4] = *(const uint4*)(arow + kc + 36);
        }
        half8 a_h[4], a_l[4];
#pragma unroll
        for (int mt = 0; mt < 4; ++mt) {
            a_h[mt] = *(const half8*)&As_h[mt * 16 + l16][quad * 8];
            a_l[mt] = *(const half8*)&As_l[mt * 16 + l16][quad * 8];
        }
        const int kq = (kc >> 3) + quad;
#pragma unroll
        for (int nt = 0; nt < 4; ++nt) {
            const size_t wi = (size_t)(kq * 256 + cb[nt] + l16) * 8;
            const half8 b_h = *(const half8*)(Wh + wi);
            const half8 b_l = *(const half8*)(Wl + wi);
#pragma unroll
            for (int mt = 0; mt < 4; ++mt)
                acc[mt][nt] = __builtin_amdgcn_mfma_f32_16x16x32_f16(a_h[mt], b_h, acc[mt][nt], 0, 0, 0);
#pragma unroll
            for (int mt = 0; mt < 4; ++mt)
                acc[mt][nt] = __builtin_amdgcn_mfma_f32_16x16x32_f16(a_l[mt], b_h, acc[mt][nt], 0, 0, 0);
#pragma unroll
            for (int mt = 0; mt < 4; ++mt)
                acc[mt][nt] = __builtin_amdgcn_mfma_f32_16x16x32_f16(a_h[mt], b_l, acc[mt][nt], 0, 0, 0);
        }
        if (ic < 9) stage_process<MASK>(pf, kc + 32 + ka, mrow, st_h, st_l);
    }

    // L1 epilogue -> H planes (no residual)
#pragma unroll
    for (int j = 0; j < 2; ++j) {
        const int c = cb[j] + l16, c2 = c + 128;
        float sc_o, sh_o, sc_g, sh_g;
        bn_fold(bn1, b1, c, sc_o, sh_o);
        bn_fold(bn1, b1, c2, sc_g, sh_g);
#pragma unroll
        for (int mt = 0; mt < 4; ++mt)
#pragma unroll
            for (int r = 0; r < 4; ++r) {
                const int sl = mt * 16 + quad * 4 + r;
                const float y = glu_val(acc[mt][j][r], acc[mt][j + 2][r], sc_o, sh_o, sc_g, sh_g);
                const half_t nh = (half_t)y;
                H_h[sl][c] = nh;
                H_l[sl][c] = (half_t)(y - (float)nh);
            }
    }
    __syncthreads();

    // ---------------- L2, L3: K=128 from H planes, residual, back to H
#pragma unroll 1
    for (int layer = 0; layer < 2; ++layer) {
        const float* bb = layer ? b3 : b2;
        const float* bn = layer ? bn3 : bn2;
        const size_t off = layer ? w3_off : (size_t)81920;
#pragma unroll
        for (int i = 0; i < 4; ++i)
#pragma unroll
            for (int j = 0; j < 4; ++j) acc[i][j] = (floatx4){0.f, 0.f, 0.f, 0.f};
#pragma unroll 1
        for (int kc = 0; kc < 128; kc += 32) {
            half8 a_h[4], a_l[4];
#pragma unroll
            for (int mt = 0; mt < 4; ++mt) {
                a_h[mt] = *(const half8*)&H_h[mt * 16 + l16][kc + quad * 8];
                a_l[mt] = *(const half8*)&H_l[mt * 16 + l16][kc + quad * 8];
            }
            const int kq = (kc >> 3) + quad;
#pragma unroll
            for (int nt = 0; nt < 4; ++nt) {
                const size_t wi = off + (size_t)(kq * 256 + cb[nt] + l16) * 8;
                const half8 b_h = *(const half8*)(Wh + wi);
                const half8 b_l = *(const half8*)(Wl + wi);
#pragma unroll
                for (int mt = 0; mt < 4; ++mt)
                    acc[mt][nt] = __builtin_amdgcn_mfma_f32_16x16x32_f16(a_h[mt], b_h, acc[mt][nt], 0, 0, 0);
#pragma unroll
                for (int mt = 0; mt < 4; ++mt)
                    acc[mt][nt] = __builtin_amdgcn_mfma_f32_16x16x32_f16(a_l[mt], b_h, acc[mt][nt], 0, 0, 0);
#pragma unroll
                for (int mt = 0; mt < 4; ++mt)
                    acc[mt][nt] = __builtin_amdgcn_mfma_f32_16x16x32_f16(a_h[mt], b_l, acc[mt][nt], 0, 0, 0);
            }
        }
        __syncthreads();     // all H reads done
#pragma unroll
        for (int j = 0; j < 2; ++j) {
            const int c = cb[j] + l16, c2 = c + 128;
            float sc_o, sh_o, sc_g, sh_g;
            bn_fold(bn, bb, c, sc_o, sh_o);
            bn_fold(bn, bb, c2, sc_g, sh_g);
#pragma unroll
            for (int mt = 0; mt < 4; ++mt)
#pragma unroll
                for (int r = 0; r < 4; ++r) {
                    const int sl = mt * 16 + quad * 4 + r;
                    const float res = (float)H_h[sl][c] + (float)H_l[sl][c];
                    const float y = (glu_val(acc[mt][j][r], acc[mt][j + 2][r], sc_o, sh_o, sc_g, sh_g) + res) * RES_SCALE_C;
                    const half_t nh = (half_t)y;
                    H_h[sl][c] = nh;
                    H_l[sl][c] = (half_t)(y - (float)nh);
                }
        }
        __syncthreads();
    }

    // ---------------- L4: K=128 from H planes, residual, outputs to global
#pragma unroll
    for (int i = 0; i < 4; ++i)
#pragma unroll
        for (int j = 0; j < 4; ++j) acc[i][j] = (floatx4){0.f, 0.f, 0.f, 0.f};
#pragma unroll 1
    for (int kc = 0; kc < 128; kc += 32) {
        half8 a_h[4], a_l[4];
#pragma unroll
        for (int mt = 0; mt < 4; ++mt) {
            a_h[mt] = *(const half8*)&H_h[mt * 16 + l16][kc + quad * 8];
            a_l[mt] = *(const half8*)&H_l[mt * 16 + l16][kc + quad * 8];
        }
        const int kq = (kc >> 3) + quad;
#pragma unroll
        for (int nt = 0; nt < 4; ++nt) {
            const size_t wi = w4_off + (size_t)(kq * 256 + cb[nt] + l16) * 8;
            const half8 b_h = *(const half8*)(Wh + wi);
            const half8 b_l = *(const half8*)(Wl + wi);
#pragma unroll
            for (int mt = 0; mt < 4; ++mt)
                acc[mt][nt] = __builtin_amdgcn_mfma_f32_16x16x32_f16(a_h[mt], b_h, acc[mt][nt], 0, 0, 0);
#pragma unroll
            for (int mt = 0; mt < 4; ++mt)
                acc[mt][nt] = __builtin_amdgcn_mfma_f32_16x16x32_f16(a_l[mt], b_h, acc[mt][nt], 0, 0, 0);
#pragma unroll
            for (int mt = 0; mt < 4; ++mt)
                acc[mt][nt] = __builtin_amdgcn_mfma_f32_16x16x32_f16(a_h[mt], b_l, acc[mt][nt], 0, 0, 0);
        }
    }
    // no further H writes; reads below are per-owning-lane
    if (w < 2) {
        if (wmode_last != 1) {
#pragma unroll
            for (int j = 0; j < 2; ++j) {
                const int c = cb[j] + l16, c2 = c + 128;   // c in [0,64)
                float sc_o, sh_o, sc_g, sh_g;
                bn_fold(bn4, b4, c, sc_o, sh_o);
                bn_fold(bn4, b4, c2, sc_g, sh_g);
#pragma unroll
                for (int mt = 0; mt < 4; ++mt)
#pragma unroll
                    for (int r = 0; r < 4; ++r) {
                        const int sl = mt * 16 + quad * 4 + r;
                        const float res = (float)H_h[sl][c] + (float)H_l[sl][c];
                        const float y = (glu_val(acc[mt][j][r], acc[mt][j + 2][r], sc_o, sh_o, sc_g, sh_g) + res) * RES_SCALE_C;
                        const float d = fmaxf(y, 0.f);
                        float* dp = ds + (size_t)(s0 + sl) * 64 + c;
                        *dp = (wmode_last == 2) ? d : (*dp + d);
                    }
            }
        }
    } else {
#pragma unroll
        for (int j = 0; j < 2; ++j) {
            const int c = cb[j] + l16, c2 = c + 128;       // c in [64,128)
            float sc_o, sh_o, sc_g, sh_g;
            bn_fold(bn4, b4, c, sc_o, sh_o);
            bn_fold(bn4, b4, c2, sc_g, sh_g);
#pragma unroll
            for (int mt = 0; mt < 4; ++mt)
#pragma unroll
                for (int r = 0; r < 4; ++r) {
                    const int sl = mt * 16 + quad * 4 + r;
                    const float res = (float)H_h[sl][c] + (float)H_l[sl][c];
                    const float y = (glu_val(acc[mt][j][r], acc[mt][j + 2][r], sc_o, sh_o, sc_g, sh_g) + res) * RES_SCALE_C;
                    avp[(size_t)(s0 + sl) * 64 + (c - 64)] = pack2(y);
                }
        }
    }
}

// ---------------- attention: split-fp16 MFMA a@W + BN + prior + bisection sparsemax ----------------
__global__ __launch_bounds__(256, 3)
void att_mfma_sparsemax(const uint32_t* __restrict__ avp,
                        const half_t* __restrict__ aWh, const half_t* __restrict__ aWl,
                        const float* __restrict__ att_b, const float* __restrict__ att_bn,
                        float* __restrict__ prior, float* __restrict__ maskg, int step)
{
    __shared__ half_t Ah[64][72];
    __shared__ half_t Al[64][72];
    __shared__ float z_lds[64][81];
    __shared__ float tau_lds[64];
    const int t = threadIdx.x, s0 = blockIdx.x * 64;
    const int w = t >> 6, lane = t & 63, quad = lane >> 4, l16 = lane & 15;

    {   // stage av (packed) -> split planes
        const int row = t >> 2, k0 = (t & 3) * 16;
        const uint32_t* src = avp + (size_t)(s0 + row) * 64 + k0;
        uint32_t wv[16];
        *(uint4*)&wv[0]  = *(const uint4*)(src);
        *(uint4*)&wv[4]  = *(const uint4*)(src + 4);
        *(uint4*)&wv[8]  = *(const uint4*)(src + 8);
        *(uint4*)&wv[12] = *(const uint4*)(src + 12);
        half8 h8[2], l8[2];
#pragma unroll
        for (int q = 0; q < 2; ++q)
#pragma unroll
            for (int j = 0; j < 8; ++j) {
                half_t h, l; unpack2(wv[q * 8 + j], h, l);
                h8[q][j] = h; l8[q][j] = l;
            }
        *(half8*)&Ah[row][k0] = h8[0]; *(half8*)&Ah[row][k0 + 8] = h8[1];
        *(half8*)&Al[row][k0] = l8[0]; *(half8*)&Al[row][k0 + 8] = l8[1];
    }
    __syncthreads();

    floatx4 acc[5];
#pragma unroll
    for (int i = 0; i < 5; ++i) acc[i] = (floatx4){0.f, 0.f, 0.f, 0.f};
    const int m0 = w * 16;
#pragma unroll
    for (int kc = 0; kc < 64; kc += 32) {
        const half8 a_h = *(const half8*)&Ah[m0 + l16][kc + quad * 8];
        const half8 a_l = *(const half8*)&Al[m0 + l16][kc + quad * 8];
        const int kq = (kc >> 3) + quad;
#pragma unroll
        for (int nt = 0; nt < 5; ++nt) {
            const size_t wi = (size_t)(kq * 80 + nt * 16 + l16) * 8;
            const half8 b_h = *(const half8*)(aWh + wi);
            const half8 b_l = *(const half8*)(aWl + wi);
            acc[nt] = __builtin_amdgcn_mfma_f32_16x16x32_f16(a_h, b_h, acc[nt], 0, 0, 0);
            acc[nt] = __builtin_amdgcn_mfma_f32_16x16x32_f16(a_l, b_h, acc[nt], 0, 0, 0);
            acc[nt] = __builtin_amdgcn_mfma_f32_16x16x32_f16(a_h, b_l, acc[nt], 0, 0, 0);
        }
    }

    // BN + prior -> z (regs + LDS)
    float zreg[5][4], preg[5][4];
#pragma unroll
    for (int nt = 0; nt < 5; ++nt) {
        const int c = nt * 16 + l16;
        const float sc = att_bn[c] * __frsqrt_rn(att_bn[240 + c] + BN_EPS_C);
        const float sh = fmaf(att_b[c] - att_bn[160 + c], sc, att_bn[80 + c]);
#pragma unroll
        for (int r = 0; r < 4; ++r) {
            const int sl = m0 + quad * 4 + r;
            const float pr = (step == 0) ? 1.f : prior[(size_t)(s0 + sl) * 80 + c];
            const float z = fmaf(acc[nt][r], sc, sh) * pr;
            zreg[nt][r] = z; preg[nt][r] = pr;
            z_lds[sl][c] = z;
        }
    }
    __syncthreads();

    // bisection sparsemax: 4 threads/sample, 20 groups each; tau err <= 2^-22
    {
        const int sl2 = t >> 2, j0 = (t & 3) * 20;
        float zj[20];
        float zmax = -1e30f;
#pragma unroll
        for (int j = 0; j < 20; ++j) { zj[j] = z_lds[sl2][j0 + j]; zmax = fmaxf(zmax, zj[j]); }
        zmax = fmaxf(zmax, __shfl_xor(zmax, 1));
        zmax = fmaxf(zmax, __shfl_xor(zmax, 2));
        float lo = zmax - 1.f, hi = zmax;
#pragma unroll 1
        for (int it = 0; it < 22; ++it) {
            const float mid = 0.5f * (lo + hi);
            float s = 0.f;
#pragma unroll
            for (int j = 0; j < 20; ++j) s += fmaxf(zj[j] - mid, 0.f);
            s += __shfl_xor(s, 1);
            s += __shfl_xor(s, 2);
            if (s >= 1.f) lo = mid; else hi = mid;
        }
        if ((t & 3) == 0) tau_lds[sl2] = 0.5f * (lo + hi);
    }
    __syncthreads();

    // mask + prior update from att-layout regs
#pragma unroll
    for (int nt = 0; nt < 5; ++nt) {
        const int c = nt * 16 + l16;
#pragma unroll
        for (int r = 0; r < 4; ++r) {
            const int sl = m0 + quad * 4 + r;
            const float mk = fmaxf(zreg[nt][r] - tau_lds[sl], 0.f);
            maskg[(size_t)(s0 + sl) * 80 + c] = mk;
            prior[(size_t)(s0 + sl) * 80 + c] = preg[nt][r] * (GAMMA_C - mk);
        }
    }
}

// ---------------- final 64 -> 1 ----------------
__global__ void final_kernel(const float* __restrict__ dsum, const float* __restrict__ out_W,
                             const float* __restrict__ out_b, float* __restrict__ out)
{
    const int s = blockIdx.x * 256 + threadIdx.x;
    float acc = out_b[0];
    const float4* dp = (const float4*)(dsum + (size_t)s * 64);
    const float4* wp = (const float4*)out_W;
#pragma unroll
    for (int q = 0; q < 16; ++q) {
        const float4 d = dp[q];
        const float4 ww = wp[q];
        acc += d.x * ww.x + d.y * ww.y + d.z * ww.z + d.w * ww.w;
    }
    out[s] = acc;
}

// ---------------- launch ----------------
extern "C" void kernel_launch(void* const* d_in, const int* in_sizes, int n_in,
                              void* d_out, int out_size, void* d_ws, size_t ws_size,
                              hipStream_t stream)
{
    const float* x_num  = (const float*)d_in[0];
    const int*   x_cat  = (const int*)d_in[1];
    const float* emb_W  = (const float*)d_in[2];
    const float* in_bn  = (const float*)d_in[3];
    const float* sh_W0  = (const float*)d_in[4];
    const float* sh_b0  = (const float*)d_in[5];
    const float* sh_bn0 = (const float*)d_in[6];
    const float* sh_W1  = (const float*)d_in[7];
    const float* sh_b1  = (const float*)d_in[8];
    const float* sh_bn1 = (const float*)d_in[9];
    const float* init_W = (const float*)d_in[10];
    const float* init_b = (const float*)d_in[11];
    const float* init_bn= (const float*)d_in[12];
    const float* step_W = (const float*)d_in[13];
    const float* step_b = (const float*)d_in[14];
    const float* step_bn= (const float*)d_in[15];
    const float* att_W  = (const float*)d_in[16];
    const float* att_b  = (const float*)d_in[17];
    const float* att_bn = (const float*)d_in[18];
    const float* out_W  = (const float*)d_in[19];
    const float* out_b  = (const float*)d_in[20];

    const size_t B = B_TOT;
    char* p = (char*)d_ws;
    uint32_t* xp  = (uint32_t*)p;  p += B * 320 * 4;
    uint32_t* avp = (uint32_t*)p;  p += B * 64 * 4;
    half_t* Wh    = (half_t*)p;    p += 507904 * 2;
    half_t* Wl    = (half_t*)p;    p += 507904 * 2;
    half_t* aWh   = (half_t*)p;    p += 25600 * 2;
    half_t* aWl   = (half_t*)p;    p += 25600 * 2;
    float* pri    = (float*)p;     p += B * 80 * 4;
    float* mg     = (float*)p;     p += B * 80 * 4;
    float* ds     = (float*)p;     p += B * 64 * 4;

    wsplit_kernel<<<1984, 256, 0, stream>>>(sh_W0, sh_W1, init_W, step_W, Wh, Wl);
    wsplit_att_kernel<<<320, 80, 0, stream>>>(att_W, aWh, aWl);
    embed_bn_kernel<<<(B_TOT * 320) / 256, 256, 0, stream>>>(x_num, x_cat, emb_W, in_bn, xp);

    const int GB = B_TOT / 64;
    // W plane offsets (halves): sh_W0=0, sh_W1=81920, init0=114688, init1=147456, step j=180224+j*32768
    ft_chain<false><<<GB, 256, 0, stream>>>(xp, nullptr, Wh, Wl,
                                            sh_b0, sh_bn0, sh_b1, sh_bn1,
                                            init_b, init_bn, init_b + 256, init_bn + 1024,
                                            (size_t)114688, (size_t)147456, avp, ds, 1);
    for (int st = 0; st < 5; ++st) {
        att_mfma_sparsemax<<<GB, 256, 0, stream>>>(avp, aWh + st * 5120, aWl + st * 5120,
                                                   att_b + st * 80, att_bn + st * 320, pri, mg, st);
        const size_t w3 = 180224 + (size_t)(st * 2 + 0) * 32768;
        const size_t w4 = 180224 + (size_t)(st * 2 + 1) * 32768;
        ft_chain<true><<<GB, 256, 0, stream>>>(xp, mg, Wh, Wl,
                                               sh_b0, sh_bn0, sh_b1, sh_bn1,
                                               step_b + (st * 2 + 0) * 256, step_bn + (st * 2 + 0) * 1024,
                                               step_b + (st * 2 + 1) * 256, step_bn + (st * 2 + 1) * 1024,
                                               w3, w4, avp, ds, st == 0 ? 2 : 3);
    }
    final_kernel<<<B_TOT / 256, 256, 0, stream>>>(ds, out_W, out_b, (float*)d_out);
}

// Round 5
// 898.195 us; speedup vs baseline: 3.2874x; 1.1344x over previous
//
#include <hip/hip_runtime.h>
#include <math.h>
#include <stdint.h>

typedef _Float16 half_t;
typedef _Float16 half8 __attribute__((ext_vector_type(8)));
typedef float floatx4 __attribute__((ext_vector_type(4)));
typedef float floatx16 __attribute__((ext_vector_type(16)));

constexpr float BN_EPS_C = 1e-5f;
constexpr float RES_SCALE_C = 0.70710678118654752f;
constexpr float GAMMA_C = 1.5f;
#define B_TOT 65536

__device__ __forceinline__ uint32_t pack2(float y) {
    const half_t h = (half_t)y;
    const half_t l = (half_t)(y - (float)h);
    union { half_t f; unsigned short u; } a, b; a.f = h; b.f = l;
    return (uint32_t)a.u | ((uint32_t)b.u << 16);
}
__device__ __forceinline__ void unpack2(uint32_t v, half_t& h, half_t& l) {
    union { unsigned short u; half_t f; } a, b;
    a.u = (unsigned short)(v & 0xffffu); b.u = (unsigned short)(v >> 16);
    h = a.f; l = b.f;
}

__global__ void wsplit_kernel(const float* __restrict__ sh_W0, const float* __restrict__ sh_W1,
                              const float* __restrict__ init_W, const float* __restrict__ step_W,
                              half_t* __restrict__ Wh, half_t* __restrict__ Wl)
{
    const int b = blockIdx.x, n = threadIdx.x;
    const float* src; int k; size_t base;
    if (b < 320)      { src = sh_W0;           k = b;       base = 0; }
    else if (b < 448) { src = sh_W1;           k = b - 320; base = 81920; }
    else if (b < 576) { src = init_W;          k = b - 448; base = 114688; }
    else if (b < 704) { src = init_W + 32768;  k = b - 576; base = 147456; }
    else {
        int j = (b - 704) >> 7; k = (b - 704) & 127;
        src = step_W + (size_t)j * 32768; base = 180224 + (size_t)j * 32768;
    }
    const float v = src[k * 256 + n];
    const half_t hi = (half_t)v;
    const half_t lo = (half_t)(v - (float)hi);
    const size_t idx = base + (size_t)(((k >> 3) * 256 + n) * 8 + (k & 7));
    Wh[idx] = hi; Wl[idx] = lo;
}

__global__ void wsplit_att_kernel(const float* __restrict__ att_W,
                                  half_t* __restrict__ aWh, half_t* __restrict__ aWl)
{
    const int b = blockIdx.x;
    const int n = threadIdx.x;
    const int step = b >> 6, k = b & 63;
    const float v = att_W[(size_t)b * 80 + n];
    const half_t h = (half_t)v;
    const half_t l = (half_t)(v - (float)h);
    const size_t idx = (size_t)step * 5120 + (size_t)(((k >> 3) * 80 + n) * 8 + (k & 7));
    aWh[idx] = h; aWl[idx] = l;
}

__global__ void embed_bn_kernel(const float* __restrict__ x_num, const int* __restrict__ x_cat,
                                const float* __restrict__ emb_W, const float* __restrict__ in_bn,
                                uint32_t* __restrict__ xp)
{
    const int idx = blockIdx.x * 256 + threadIdx.x;
    const int s = idx / 320, j = idx - s * 320;
    float v;
    if (j < 64) v = x_num[(size_t)s * 64 + j];
    else {
        const int c = (j - 64) >> 4, e = (j - 64) & 15;
        v = emb_W[(size_t)(c * 1000 + x_cat[(size_t)s * 16 + c]) * 16 + e];
    }
    const float val = (v - in_bn[640 + j]) * (in_bn[j] * __frsqrt_rn(in_bn[960 + j] + BN_EPS_C)) + in_bn[320 + j];
    xp[idx] = pack2(val);
}

template<bool MASK>
__device__ __forceinline__ void stage_process(const uint32_t* pf, int kb, const float* mrow,
                                              half8& hh, half8& ll)
{
    if (MASK) {
        float m[8];
        if (kb < 64) {
            const float4 m0 = *(const float4*)(mrow + kb);
            const float4 m1 = *(const float4*)(mrow + kb + 4);
            m[0] = m0.x; m[1] = m0.y; m[2] = m0.z; m[3] = m0.w;
            m[4] = m1.x; m[5] = m1.y; m[6] = m1.z; m[7] = m1.w;
        } else {
            const float mm = mrow[64 + ((kb - 64) >> 4)];
#pragma unroll
            for (int j = 0; j < 8; ++j) m[j] = mm;
        }
#pragma unroll
        for (int j = 0; j < 8; ++j) {
            half_t h, l; unpack2(pf[j], h, l);
            const float v = ((float)h + (float)l) * m[j];
            const half_t nh = (half_t)v;
            hh[j] = nh; ll[j] = (half_t)(v - (float)nh);
        }
    } else {
#pragma unroll
        for (int j = 0; j < 8; ++j) {
            half_t h, l; unpack2(pf[j], h, l);
            hh[j] = h; ll[j] = l;
        }
    }
}

__device__ __forceinline__ void bn_fold(const float* __restrict__ bn, const float* __restrict__ bias,
                                        int c, float& sc, float& sh)
{
    sc = bn[c] * __frsqrt_rn(bn[768 + c] + BN_EPS_C);
    sh = fmaf(bias[c] - bn[512 + c], sc, bn[256 + c]);
}

__device__ __forceinline__ float glu_val(float accO, float accG,
                                         float sc_o, float sh_o, float sc_g, float sh_g)
{
    const float o = fmaf(accO, sc_o, sh_o);
    const float g = fmaf(accG, sc_g, sh_g);
    const float e = __expf(-g);
    return o * __builtin_amdgcn_rcpf(1.f + e);
}

#define MFMA32(A, B, C) C = __builtin_amdgcn_mfma_f32_32x32x16_f16(A, B, C, 0, 0, 0)

__device__ __forceinline__ void mfma_slice(const half8 a_h[2], const half8 a_l[2],
                                           const half8& bo_h, const half8& bo_l,
                                           const half8& bg_h, const half8& bg_l,
                                           floatx16 accO[2], floatx16 accG[2])
{
    MFMA32(a_h[0], bo_h, accO[0]);
    MFMA32(a_h[1], bo_h, accO[1]);
    MFMA32(a_h[0], bg_h, accG[0]);
    MFMA32(a_h[1], bg_h, accG[1]);
    MFMA32(a_l[0], bo_h, accO[0]);
    MFMA32(a_l[1], bo_h, accO[1]);
    MFMA32(a_l[0], bg_h, accG[0]);
    MFMA32(a_l[1], bg_h, accG[1]);
    MFMA32(a_h[0], bo_l, accO[0]);
    MFMA32(a_h[1], bo_l, accO[1]);
    MFMA32(a_h[0], bg_l, accG[0]);
    MFMA32(a_h[1], bg_l, accG[1]);
}

template<bool MASK>
__global__ __launch_bounds__(256, 3)
void ft_chain(const uint32_t* __restrict__ xp, const float* __restrict__ mg,
              const half_t* __restrict__ Wh, const half_t* __restrict__ Wl,
              const float* __restrict__ b1, const float* __restrict__ bn1,
              const float* __restrict__ b2, const float* __restrict__ bn2,
              const float* __restrict__ b3, const float* __restrict__ bn3,
              const float* __restrict__ b4, const float* __restrict__ bn4,
              size_t w3_off, size_t w4_off,
              uint32_t* __restrict__ avp, float* __restrict__ ds, int wmode_last)
{
    __shared__ half_t As_h[64][48];
    __shared__ half_t As_l[64][48];
    __shared__ half_t H_h[64][136];
    __shared__ half_t H_l[64][136];

    const int t = threadIdx.x;
    const int s0 = blockIdx.x * 64;
    const int w = t >> 6, lane = t & 63;
    const int n32 = lane & 31, k8 = lane >> 5;
    const int no = 32 * w;
    const int r4 = (blockIdx.x >> 8) & 3;

    floatx16 accO[2], accG[2];
#pragma unroll
    for (int i = 0; i < 2; ++i) { accO[i] = (floatx16)(0.f); accG[i] = (floatx16)(0.f); }

    const int ra = t >> 2, ka = (t & 3) * 8;
    const uint32_t* arow = xp + (size_t)(s0 + ra) * 320 + ka;
    const float* mrow = MASK ? (mg + (size_t)(s0 + ra) * 80) : nullptr;

    int ic = (r4 * 5) >> 1;
    uint32_t pf[8];
    *(uint4*)&pf[0] = *(const uint4*)(arow + ic * 32);
    *(uint4*)&pf[4] = *(const uint4*)(arow + ic * 32 + 4);
    half8 st_h, st_l;
    stage_process<MASK>(pf, ic * 32 + ka, mrow, st_h, st_l);

#pragma unroll 1
    for (int i = 0; i < 10; ++i) {
        const int icn = (ic + 1 == 10) ? 0 : ic + 1;
        __syncthreads();
        *(half8*)&As_h[ra][ka] = st_h;
        *(half8*)&As_l[ra][ka] = st_l;
        __syncthreads();
        if (i < 9) {
            *(uint4*)&pf[0] = *(const uint4*)(arow + icn * 32);
            *(uint4*)&pf[4] = *(const uint4*)(arow + icn * 32 + 4);
        }
        half8 a_h[2][2], a_l[2][2];
#pragma unroll
        for (int mt = 0; mt < 2; ++mt)
#pragma unroll
            for (int kh = 0; kh < 2; ++kh) {
                a_h[mt][kh] = *(const half8*)&As_h[mt * 32 + n32][kh * 16 + k8 * 8];
                a_l[mt][kh] = *(const half8*)&As_l[mt * 32 + n32][kh * 16 + k8 * 8];
            }
        const int kq0 = ic * 4 + k8;
#pragma unroll
        for (int kh = 0; kh < 2; ++kh) {
            const size_t wo = (size_t)((kq0 + kh * 2) * 256 + no + n32) * 8;
            const half8 bo_h = *(const half8*)(Wh + wo);
            const half8 bo_l = *(const half8*)(Wl + wo);
            const half8 bg_h = *(const half8*)(Wh + wo + 1024);
            const half8 bg_l = *(const half8*)(Wl + wo + 1024);
            half8 ah2[2] = { a_h[0][kh], a_h[1][kh] };
            half8 al2[2] = { a_l[0][kh], a_l[1][kh] };
            mfma_slice(ah2, al2, bo_h, bo_l, bg_h, bg_l, accO, accG);
        }
        if (i < 9) stage_process<MASK>(pf, icn * 32 + ka, mrow, st_h, st_l);
        ic = icn;
    }

    {
        const int c = no + n32;
        float sc_o, sh_o, sc_g, sh_g;
        bn_fold(bn1, b1, c, sc_o, sh_o);
        bn_fold(bn1, b1, c + 128, sc_g, sh_g);
#pragma unroll
        for (int mt = 0; mt < 2; ++mt)
#pragma unroll
            for (int reg = 0; reg < 16; ++reg) {
                const int sl = mt * 32 + (reg & 3) + 8 * (reg >> 2) + 4 * k8;
                const float y = glu_val(accO[mt][reg], accG[mt][reg], sc_o, sh_o, sc_g, sh_g);
                const half_t nh = (half_t)y;
                H_h[sl][c] = nh;
                H_l[sl][c] = (half_t)(y - (float)nh);
            }
    }
    __syncthreads();

#pragma unroll 1
    for (int layer = 0; layer < 2; ++layer) {
        const float* bb = layer ? b3 : b2;
        const float* bn = layer ? bn3 : bn2;
        const size_t off = layer ? w3_off : (size_t)81920;
#pragma unroll
        for (int i = 0; i < 2; ++i) { accO[i] = (floatx16)(0.f); accG[i] = (floatx16)(0.f); }
#pragma unroll 1
        for (int i = 0; i < 4; ++i) {
            const int icc = (r4 + i) & 3;
            const int kc = icc * 32;
            half8 a_h[2][2], a_l[2][2];
#pragma unroll
            for (int mt = 0; mt < 2; ++mt)
#pragma unroll
                for (int kh = 0; kh < 2; ++kh) {
                    a_h[mt][kh] = *(const half8*)&H_h[mt * 32 + n32][kc + kh * 16 + k8 * 8];
                    a_l[mt][kh] = *(const half8*)&H_l[mt * 32 + n32][kc + kh * 16 + k8 * 8];
                }
            const int kq0 = icc * 4 + k8;
#pragma unroll
            for (int kh = 0; kh < 2; ++kh) {
                const size_t wo = off + (size_t)((kq0 + kh * 2) * 256 + no + n32) * 8;
                const half8 bo_h = *(const half8*)(Wh + wo);
                const half8 bo_l = *(const half8*)(Wl + wo);
                const half8 bg_h = *(const half8*)(Wh + wo + 1024);
                const half8 bg_l = *(const half8*)(Wl + wo + 1024);
                half8 ah2[2] = { a_h[0][kh], a_h[1][kh] };
                half8 al2[2] = { a_l[0][kh], a_l[1][kh] };
                mfma_slice(ah2, al2, bo_h, bo_l, bg_h, bg_l, accO, accG);
            }
        }
        __syncthreads();
        {
            const int c = no + n32;
            float sc_o, sh_o, sc_g, sh_g;
            bn_fold(bn, bb, c, sc_o, sh_o);
            bn_fold(bn, bb, c + 128, sc_g, sh_g);
#pragma unroll
            for (int mt = 0; mt < 2; ++mt)
#pragma unroll
                for (int reg = 0; reg < 16; ++reg) {
                    const int sl = mt * 32 + (reg & 3) + 8 * (reg >> 2) + 4 * k8;
                    const float res = (float)H_h[sl][c] + (float)H_l[sl][c];
                    const float y = (glu_val(accO[mt][reg], accG[mt][reg], sc_o, sh_o, sc_g, sh_g) + res) * RES_SCALE_C;
                    const half_t nh = (half_t)y;
                    H_h[sl][c] = nh;
                    H_l[sl][c] = (half_t)(y - (float)nh);
                }
        }
        __syncthreads();
    }

#pragma unroll
    for (int i = 0; i < 2; ++i) { accO[i] = (floatx16)(0.f); accG[i] = (floatx16)(0.f); }
#pragma unroll 1
    for (int i = 0; i < 4; ++i) {
        const int icc = (r4 + i) & 3;
        const int kc = icc * 32;
        half8 a_h[2][2], a_l[2][2];
#pragma unroll
        for (int mt = 0; mt < 2; ++mt)
#pragma unroll
            for (int kh = 0; kh < 2; ++kh) {
                a_h[mt][kh] = *(const half8*)&H_h[mt * 32 + n32][kc + kh * 16 + k8 * 8];
                a_l[mt][kh] = *(const half8*)&H_l[mt * 32 + n32][kc + kh * 16 + k8 * 8];
            }
        const int kq0 = icc * 4 + k8;
#pragma unroll
        for (int kh = 0; kh < 2; ++kh) {
            const size_t wo = w4_off + (size_t)((kq0 + kh * 2) * 256 + no + n32) * 8;
            const half8 bo_h = *(const half8*)(Wh + wo);
            const half8 bo_l = *(const half8*)(Wl + wo);
            const half8 bg_h = *(const half8*)(Wh + wo + 1024);
            const half8 bg_l = *(const half8*)(Wl + wo + 1024);
            half8 ah2[2] = { a_h[0][kh], a_h[1][kh] };
            half8 al2[2] = { a_l[0][kh], a_l[1][kh] };
            mfma_slice(ah2, al2, bo_h, bo_l, bg_h, bg_l, accO, accG);
        }
    }
    {
        const int c = no + n32;
        float sc_o, sh_o, sc_g, sh_g;
        bn_fold(bn4, b4, c, sc_o, sh_o);
        bn_fold(bn4, b4, c + 128, sc_g, sh_g);
        if (w < 2) {
            if (wmode_last != 1) {
#pragma unroll
                for (int mt = 0; mt < 2; ++mt)
#pragma unroll
                    for (int reg = 0; reg < 16; ++reg) {
                        const int sl = mt * 32 + (reg & 3) + 8 * (reg >> 2) + 4 * k8;
                        const float res = (float)H_h[sl][c] + (float)H_l[sl][c];
                        const float y = (glu_val(accO[mt][reg], accG[mt][reg], sc_o, sh_o, sc_g, sh_g) + res) * RES_SCALE_C;
                        const float d = fmaxf(y, 0.f);
                        float* dp = ds + (size_t)(s0 + sl) * 64 + c;
                        *dp = (wmode_last == 2) ? d : (*dp + d);
                    }
            }
        } else {
#pragma unroll
            for (int mt = 0; mt < 2; ++mt)
#pragma unroll
                for (int reg = 0; reg < 16; ++reg) {
                    const int sl = mt * 32 + (reg & 3) + 8 * (reg >> 2) + 4 * k8;
                    const float res = (float)H_h[sl][c] + (float)H_l[sl][c];
                    const float y = (glu_val(accO[mt][reg], accG[mt][reg], sc_o, sh_o, sc_g, sh_g) + res) * RES_SCALE_C;
                    avp[(size_t)(s0 + sl) * 64 + (c - 64)] = pack2(y);
                }
        }
    }
}

__global__ __launch_bounds__(256, 3)
void att_mfma_sparsemax(const uint32_t* __restrict__ avp,
                        const half_t* __restrict__ aWh, const half_t* __restrict__ aWl,
                        const float* __restrict__ att_b, const float* __restrict__ att_bn,
                        float* __restrict__ prior, float* __restrict__ maskg, int step)
{
    __shared__ half_t Ah[64][72];
    __shared__ half_t Al[64][72];
    __shared__ float z_lds[64][81];
    __shared__ float tau_lds[64];
    const int t = threadIdx.x, s0 = blockIdx.x * 64;
    const int w = t >> 6, lane = t & 63, quad = lane >> 4, l16 = lane & 15;

    {
        const int row = t >> 2, k0 = (t & 3) * 16;
        const uint32_t* src = avp + (size_t)(s0 + row) * 64 + k0;
        uint32_t wv[16];
        *(uint4*)&wv[0]  = *(const uint4*)(src);
        *(uint4*)&wv[4]  = *(const uint4*)(src + 4);
        *(uint4*)&wv[8]  = *(const uint4*)(src + 8);
        *(uint4*)&wv[12] = *(const uint4*)(src + 12);
        half8 h8[2], l8[2];
#pragma unroll
        for (int q = 0; q < 2; ++q)
#pragma unroll
            for (int j = 0; j < 8; ++j) {
                half_t h, l; unpack2(wv[q * 8 + j], h, l);
                h8[q][j] = h; l8[q][j] = l;
            }
        *(half8*)&Ah[row][k0] = h8[0]; *(half8*)&Ah[row][k0 + 8] = h8[1];
        *(half8*)&Al[row][k0] = l8[0]; *(half8*)&Al[row][k0 + 8] = l8[1];
    }
    __syncthreads();

    floatx4 acc[5];
#pragma unroll
    for (int i = 0; i < 5; ++i) acc[i] = (floatx4){0.f, 0.f, 0.f, 0.f};
    const int m0 = w * 16;
#pragma unroll
    for (int kc = 0; kc < 64; kc += 32) {
        const half8 a_h = *(const half8*)&Ah[m0 + l16][kc + quad * 8];
        const half8 a_l = *(const half8*)&Al[m0 + l16][kc + quad * 8];
        const int kq = (kc >> 3) + quad;
#pragma unroll
        for (int nt = 0; nt < 5; ++nt) {
            const size_t wi = (size_t)(kq * 80 + nt * 16 + l16) * 8;
            const half8 b_h = *(const half8*)(aWh + wi);
            const half8 b_l = *(const half8*)(aWl + wi);
            acc[nt] = __builtin_amdgcn_mfma_f32_16x16x32_f16(a_h, b_h, acc[nt], 0, 0, 0);
            acc[nt] = __builtin_amdgcn_mfma_f32_16x16x32_f16(a_l, b_h, acc[nt], 0, 0, 0);
            acc[nt] = __builtin_amdgcn_mfma_f32_16x16x32_f16(a_h, b_l, acc[nt], 0, 0, 0);
        }
    }

    float zreg[5][4], preg[5][4];
#pragma unroll
    for (int nt = 0; nt < 5; ++nt) {
        const int c = nt * 16 + l16;
        const float sc = att_bn[c] * __frsqrt_rn(att_bn[240 + c] + BN_EPS_C);
        const float sh = fmaf(att_b[c] - att_bn[160 + c], sc, att_bn[80 + c]);
#pragma unroll
        for (int r = 0; r < 4; ++r) {
            const int sl = m0 + quad * 4 + r;
            const float pr = (step == 0) ? 1.f : prior[(size_t)(s0 + sl) * 80 + c];
            const float z = fmaf(acc[nt][r], sc, sh) * pr;
            zreg[nt][r] = z; preg[nt][r] = pr;
            z_lds[sl][c] = z;
        }
    }
    __syncthreads();

    {
        const int sl2 = t >> 2, j0 = (t & 3) * 20;
        float zj[20];
        float zmax = -1e30f;
#pragma unroll
        for (int j = 0; j < 20; ++j) { zj[j] = z_lds[sl2][j0 + j]; zmax = fmaxf(zmax, zj[j]); }
        zmax = fmaxf(zmax, __shfl_xor(zmax, 1));
        zmax = fmaxf(zmax, __shfl_xor(zmax, 2));
        float lo = zmax - 1.f, hi = zmax;
#pragma unroll 1
        for (int it = 0; it < 22; ++it) {
            const float mid = 0.5f * (lo + hi);
            float s = 0.f;
#pragma unroll
            for (int j = 0; j < 20; ++j) s += fmaxf(zj[j] - mid, 0.f);
            s += __shfl_xor(s, 1);
            s += __shfl_xor(s, 2);
            if (s >= 1.f) lo = mid; else hi = mid;
        }
        if ((t & 3) == 0) tau_lds[sl2] = 0.5f * (lo + hi);
    }
    __syncthreads();

#pragma unroll
    for (int nt = 0; nt < 5; ++nt) {
        const int c = nt * 16 + l16;
#pragma unroll
        for (int r = 0; r < 4; ++r) {
            const int sl = m0 + quad * 4 + r;
            const float mk = fmaxf(zreg[nt][r] - tau_lds[sl], 0.f);
            maskg[(size_t)(s0 + sl) * 80 + c] = mk;
            prior[(size_t)(s0 + sl) * 80 + c] = preg[nt][r] * (GAMMA_C - mk);
        }
    }
}

__global__ void final_kernel(const float* __restrict__ dsum, const float* __restrict__ out_W,
                             const float* __restrict__ out_b, float* __restrict__ out)
{
    const int s = blockIdx.x * 256 + threadIdx.x;
    float acc = out_b[0];
    const float4* dp = (const float4*)(dsum + (size_t)s * 64);
    const float4* wp = (const float4*)out_W;
#pragma unroll
    for (int q = 0; q < 16; ++q) {
        const float4 d = dp[q];
        const float4 ww = wp[q];
        acc += d.x * ww.x + d.y * ww.y + d.z * ww.z + d.w * ww.w;
    }
    out[s] = acc;
}

extern "C" void kernel_launch(void* const* d_in, const int* in_sizes, int n_in,
                              void* d_out, int out_size, void* d_ws, size_t ws_size,
                              hipStream_t stream)
{
    const float* x_num  = (const float*)d_in[0];
    const int*   x_cat  = (const int*)d_in[1];
    const float* emb_W  = (const float*)d_in[2];
    const float* in_bn  = (const float*)d_in[3];
    const float* sh_W0  = (const float*)d_in[4];
    const float* sh_b0  = (const float*)d_in[5];
    const float* sh_bn0 = (const float*)d_in[6];
    const float* sh_W1  = (const float*)d_in[7];
    const float* sh_b1  = (const float*)d_in[8];
    const float* sh_bn1 = (const float*)d_in[9];
    const float* init_W = (const float*)d_in[10];
    const float* init_b = (const float*)d_in[11];
    const float* init_bn= (const float*)d_in[12];
    const float* step_W = (const float*)d_in[13];
    const float* step_b = (const float*)d_in[14];
    const float* step_bn= (const float*)d_in[15];
    const float* att_W  = (const float*)d_in[16];
    const float* att_b  = (const float*)d_in[17];
    const float* att_bn = (const float*)d_in[18];
    const float* out_W  = (const float*)d_in[19];
    const float* out_b  = (const float*)d_in[20];

    const size_t B = B_TOT;
    char* p = (char*)d_ws;
    uint32_t* xp  = (uint32_t*)p;  p += B * 320 * 4;
    uint32_t* avp = (uint32_t*)p;  p += B * 64 * 4;
    half_t* Wh    = (half_t*)p;    p += 507904 * 2;
    half_t* Wl    = (half_t*)p;    p += 507904 * 2;
    half_t* aWh   = (half_t*)p;    p += 25600 * 2;
    half_t* aWl   = (half_t*)p;    p += 25600 * 2;
    float* pri    = (float*)p;     p += B * 80 * 4;
    float* mg     = (float*)p;     p += B * 80 * 4;
    float* ds     = (float*)p;     p += B * 64 * 4;

    wsplit_kernel<<<1984, 256, 0, stream>>>(sh_W0, sh_W1, init_W, step_W, Wh, Wl);
    wsplit_att_kernel<<<320, 80, 0, stream>>>(att_W, aWh, aWl);
    embed_bn_kernel<<<(B_TOT * 320) / 256, 256, 0, stream>>>(x_num, x_cat, emb_W, in_bn, xp);

    const int GB = B_TOT / 64;
    ft_chain<false><<<GB, 256, 0, stream>>>(xp, nullptr, Wh, Wl,
                                            sh_b0, sh_bn0, sh_b1, sh_bn1,
                                            init_b, init_bn, init_b + 256, init_bn + 1024,
                                            (size_t)114688, (size_t)147456, avp, ds, 1);
    for (int st = 0; st < 5; ++st) {
        att_mfma_sparsemax<<<GB, 256, 0, stream>>>(avp, aWh + st * 5120, aWl + st * 5120,
                                                   att_b + st * 80, att_bn + st * 320, pri, mg, st);
        const size_t w3 = 180224 + (size_t)(st * 2 + 0) * 32768;
        const size_t w4 = 180224 + (size_t)(st * 2 + 1) * 32768;
        ft_chain<true><<<GB, 256, 0, stream>>>(xp, mg, Wh, Wl,
                                               sh_b0, sh_bn0, sh_b1, sh_bn1,
                                               step_b + (st * 2 + 0) * 256, step_bn + (st * 2 + 0) * 1024,
                                               step_b + (st * 2 + 1) * 256, step_bn + (st * 2 + 1) * 1024,
                                               w3, w4, avp, ds, st == 0 ? 2 : 3);
    }
    final_kernel<<<B_TOT / 256, 256, 0, stream>>>(ds, out_W, out_b, (float*)d_out);
}

// Round 6
// 778.495 us; speedup vs baseline: 3.7929x; 1.1538x over previous
//
#include <hip/hip_runtime.h>
#include <math.h>
#include <stdint.h>

typedef _Float16 half_t;
typedef _Float16 half8 __attribute__((ext_vector_type(8)));
typedef float floatx4 __attribute__((ext_vector_type(4)));
typedef float floatx16 __attribute__((ext_vector_type(16)));

constexpr float BN_EPS_C = 1e-5f;
constexpr float RES_SCALE_C = 0.70710678118654752f;
constexpr float GAMMA_C = 1.5f;
#define B_TOT 65536

// ---------------- packed (hi,lo) fp16-pair helpers ----------------
__device__ __forceinline__ uint32_t pack2(float y) {
    const half_t h = (half_t)y;
    const half_t l = (half_t)(y - (float)h);
    union { half_t f; unsigned short u; } a, b; a.f = h; b.f = l;
    return (uint32_t)a.u | ((uint32_t)b.u << 16);
}
__device__ __forceinline__ void unpack2(uint32_t v, half_t& h, half_t& l) {
    union { unsigned short u; half_t f; } a, b;
    a.u = (unsigned short)(v & 0xffffu); b.u = (unsigned short)(v >> 16);
    h = a.f; l = b.f;
}

// ---------------- W split+repack (fragment-major 8-granule, hi/lo planes) ----------------
__global__ void wsplit_kernel(const float* __restrict__ sh_W0, const float* __restrict__ sh_W1,
                              const float* __restrict__ init_W, const float* __restrict__ step_W,
                              half_t* __restrict__ Wh, half_t* __restrict__ Wl)
{
    const int b = blockIdx.x, n = threadIdx.x;
    const float* src; int k; size_t base;
    if (b < 320)      { src = sh_W0;           k = b;       base = 0; }
    else if (b < 448) { src = sh_W1;           k = b - 320; base = 81920; }
    else if (b < 576) { src = init_W;          k = b - 448; base = 114688; }
    else if (b < 704) { src = init_W + 32768;  k = b - 576; base = 147456; }
    else {
        int j = (b - 704) >> 7; k = (b - 704) & 127;
        src = step_W + (size_t)j * 32768; base = 180224 + (size_t)j * 32768;
    }
    const float v = src[k * 256 + n];
    const half_t hi = (half_t)v;
    const half_t lo = (half_t)(v - (float)hi);
    const size_t idx = base + (size_t)(((k >> 3) * 256 + n) * 8 + (k & 7));
    Wh[idx] = hi; Wl[idx] = lo;
}

__global__ void wsplit_att_kernel(const float* __restrict__ att_W,
                                  half_t* __restrict__ aWh, half_t* __restrict__ aWl)
{
    const int b = blockIdx.x;        // step*64 + k
    const int n = threadIdx.x;       // 0..79
    const int step = b >> 6, k = b & 63;
    const float v = att_W[(size_t)b * 80 + n];
    const half_t h = (half_t)v;
    const half_t l = (half_t)(v - (float)h);
    const size_t idx = (size_t)step * 5120 + (size_t)(((k >> 3) * 80 + n) * 8 + (k & 7));
    aWh[idx] = h; aWl[idx] = l;
}

__global__ void embed_bn_kernel(const float* __restrict__ x_num, const int* __restrict__ x_cat,
                                const float* __restrict__ emb_W, const float* __restrict__ in_bn,
                                uint32_t* __restrict__ xp)
{
    const int idx = blockIdx.x * 256 + threadIdx.x;
    const int s = idx / 320, j = idx - s * 320;
    float v;
    if (j < 64) v = x_num[(size_t)s * 64 + j];
    else {
        const int c = (j - 64) >> 4, e = (j - 64) & 15;
        v = emb_W[(size_t)(c * 1000 + x_cat[(size_t)s * 16 + c]) * 16 + e];
    }
    const float val = (v - in_bn[640 + j]) * (in_bn[j] * __frsqrt_rn(in_bn[960 + j] + BN_EPS_C)) + in_bn[320 + j];
    xp[idx] = pack2(val);
}

__device__ __forceinline__ void bn_fold(const float* __restrict__ bn, const float* __restrict__ bias,
                                        int c, float& sc, float& sh)
{
    sc = bn[c] * __frsqrt_rn(bn[768 + c] + BN_EPS_C);
    sh = fmaf(bias[c] - bn[512 + c], sc, bn[256 + c]);
}

__device__ __forceinline__ float glu_val(float accO, float accG,
                                         float sc_o, float sh_o, float sc_g, float sh_g)
{
    const float o = fmaf(accO, sc_o, sh_o);
    const float g = fmaf(accG, sc_g, sh_g);
    const float e = __expf(-g);
    return o * __builtin_amdgcn_rcpf(1.f + e);
}

#define MFMA32(A, B, C) C = __builtin_amdgcn_mfma_f32_32x32x16_f16(A, B, C, 0, 0, 0)
#define MFMA16(A, B, C) C = __builtin_amdgcn_mfma_f32_16x16x32_f16(A, B, C, 0, 0, 0)

// K=128 layer accumulate from H planes (8 slices of 16-k, rotated start)
__device__ __forceinline__ void layer_accum(const half_t (*H_h)[136], const half_t (*H_l)[136],
                                            const half_t* __restrict__ Wh, const half_t* __restrict__ Wl,
                                            size_t off, int n32, int k8, int no, int rot,
                                            floatx16* accO, floatx16* accG)
{
#pragma unroll 1
    for (int s = 0; s < 8; ++s) {
        const int sl8 = (s + rot) & 7;
        const int kq = sl8 * 2 + k8;
        const size_t wo = off + (size_t)(kq * 256 + no + n32) * 8;
        const half8 bo_h = *(const half8*)(Wh + wo);
        const half8 bo_l = *(const half8*)(Wl + wo);
        const half8 bg_h = *(const half8*)(Wh + wo + 1024);
        const half8 bg_l = *(const half8*)(Wl + wo + 1024);
#pragma unroll
        for (int mt = 0; mt < 4; ++mt) {
            const half8 a_h = *(const half8*)&H_h[mt * 32 + n32][sl8 * 16 + k8 * 8];
            const half8 a_l = *(const half8*)&H_l[mt * 32 + n32][sl8 * 16 + k8 * 8];
            MFMA32(a_h, bo_h, accO[mt]); MFMA32(a_h, bg_h, accG[mt]);
            MFMA32(a_l, bo_h, accO[mt]); MFMA32(a_l, bg_h, accG[mt]);
            MFMA32(a_h, bo_l, accO[mt]); MFMA32(a_h, bg_l, accG[mt]);
        }
    }
}

// ---------------- fused (att+sparsemax) + FT chain, 128 samples/block ----------------
template<bool MASK>
__global__ __launch_bounds__(256, 2)
void ft_chain(const uint32_t* __restrict__ xp, uint32_t* __restrict__ avp,
              const half_t* __restrict__ Wh, const half_t* __restrict__ Wl,
              const half_t* __restrict__ aWh, const half_t* __restrict__ aWl,
              const float* __restrict__ att_b, const float* __restrict__ att_bn,
              float* __restrict__ prior,
              const float* __restrict__ b1, const float* __restrict__ bn1,
              const float* __restrict__ b2, const float* __restrict__ bn2,
              const float* __restrict__ b3, const float* __restrict__ bn3,
              const float* __restrict__ b4, const float* __restrict__ bn4,
              size_t w3_off, size_t w4_off,
              float* __restrict__ ds, int wmode_last, int step)
{
    // LDS region plan (79872 B total, overlaid in time):
    //  [0,43008)        mgs float[128][84]      (mask; live att-z -> end of L1 staging)
    //  [43008,79872)    As planes [128][72]x2   (L1 chunk tile) / Apk uint32[128][68] (att stage)
    //  [0,69632)        H planes [128][136]x2   (written at L1 epilogue, after all above dead)
    __shared__ __align__(16) char smem[79872];
    float    (*mgs)[84]  = (float    (*)[84])smem;
    half_t   (*As_h)[72] = (half_t   (*)[72])(smem + 43008);
    half_t   (*As_l)[72] = (half_t   (*)[72])(smem + 61440);
    uint32_t (*Apk)[68]  = (uint32_t (*)[68])(smem + 43008);
    half_t   (*H_h)[136] = (half_t   (*)[136])smem;
    half_t   (*H_l)[136] = (half_t   (*)[136])(smem + 34816);

    const int t = threadIdx.x;
    const int s0 = blockIdx.x * 128;
    const int w = t >> 6, lane = t & 63;
    const int n32 = lane & 31, k8 = lane >> 5;
    const int quad = lane >> 4, l16 = lane & 15;
    const int no = 32 * w;
    const int half_id = (blockIdx.x >> 8) & 1;
    const int row = t >> 1, k0 = (t & 1) * 32;

    if (MASK) {
        // ---- stage avp (packed) -> Apk
        {
            const uint4* src = (const uint4*)(avp + (size_t)(s0 + row) * 64 + k0);
            uint4* dst = (uint4*)&Apk[row][k0];
#pragma unroll
            for (int q = 0; q < 8; ++q) dst[q] = src[q];
        }
        __syncthreads();
        // ---- z = BN(a@attW + b) * prior  (16x16x32, 2 m-tiles x 5 n-tiles per wave)
        floatx4 zacc[2][5];
#pragma unroll
        for (int mt = 0; mt < 2; ++mt)
#pragma unroll
            for (int nt = 0; nt < 5; ++nt) zacc[mt][nt] = (floatx4){0.f, 0.f, 0.f, 0.f};
#pragma unroll
        for (int kc = 0; kc < 64; kc += 32) {
            half8 a_h[2], a_l[2];
#pragma unroll
            for (int mt = 0; mt < 2; ++mt) {
                uint32_t wv[8];
                *(uint4*)&wv[0] = *(const uint4*)&Apk[w * 32 + mt * 16 + l16][kc + quad * 8];
                *(uint4*)&wv[4] = *(const uint4*)&Apk[w * 32 + mt * 16 + l16][kc + quad * 8 + 4];
#pragma unroll
                for (int j = 0; j < 8; ++j) { half_t h, l; unpack2(wv[j], h, l); a_h[mt][j] = h; a_l[mt][j] = l; }
            }
            const int kq = (kc >> 3) + quad;
#pragma unroll
            for (int nt = 0; nt < 5; ++nt) {
                const size_t wi = (size_t)(kq * 80 + nt * 16 + l16) * 8;
                const half8 b_h = *(const half8*)(aWh + wi);
                const half8 b_l = *(const half8*)(aWl + wi);
#pragma unroll
                for (int mt = 0; mt < 2; ++mt) {
                    MFMA16(a_h[mt], b_h, zacc[mt][nt]);
                    MFMA16(a_l[mt], b_h, zacc[mt][nt]);
                    MFMA16(a_h[mt], b_l, zacc[mt][nt]);
                }
            }
        }
        float preg[2][5][4];
#pragma unroll
        for (int nt = 0; nt < 5; ++nt) {
            const int c = nt * 16 + l16;
            const float sc = att_bn[c] * __frsqrt_rn(att_bn[240 + c] + BN_EPS_C);
            const float sh = fmaf(att_b[c] - att_bn[160 + c], sc, att_bn[80 + c]);
#pragma unroll
            for (int mt = 0; mt < 2; ++mt)
#pragma unroll
                for (int r = 0; r < 4; ++r) {
                    const int sl = w * 32 + mt * 16 + quad * 4 + r;
                    const float pr = (step == 0) ? 1.f : prior[(size_t)(s0 + sl) * 80 + c];
                    preg[mt][nt][r] = pr;
                    mgs[sl][c] = fmaf(zacc[mt][nt][r], sc, sh) * pr;
                }
        }
        __syncthreads();
        // ---- bisection sparsemax: 2 threads/sample, 40 groups each; overwrite z with mask
        {
            const int samp = row, j0 = (t & 1) * 40;
            float zj[40], zmax = -1e30f;
#pragma unroll
            for (int j = 0; j < 40; ++j) { zj[j] = mgs[samp][j0 + j]; zmax = fmaxf(zmax, zj[j]); }
            zmax = fmaxf(zmax, __shfl_xor(zmax, 1));
            float lo = zmax - 1.f, hi = zmax;
#pragma unroll 1
            for (int it = 0; it < 22; ++it) {
                const float mid = 0.5f * (lo + hi);
                float ssum = 0.f;
#pragma unroll
                for (int j = 0; j < 40; ++j) ssum += fmaxf(zj[j] - mid, 0.f);
                ssum += __shfl_xor(ssum, 1);
                if (ssum >= 1.f) lo = mid; else hi = mid;
            }
            const float tau = 0.5f * (lo + hi);
#pragma unroll
            for (int j = 0; j < 40; ++j) mgs[samp][j0 + j] = fmaxf(zj[j] - tau, 0.f);
        }
        __syncthreads();
        // ---- prior update (mask read back from LDS)
#pragma unroll
        for (int nt = 0; nt < 5; ++nt) {
            const int c = nt * 16 + l16;
#pragma unroll
            for (int mt = 0; mt < 2; ++mt)
#pragma unroll
                for (int r = 0; r < 4; ++r) {
                    const int sl = w * 32 + mt * 16 + quad * 4 + r;
                    prior[(size_t)(s0 + sl) * 80 + c] = preg[mt][nt][r] * (GAMMA_C - mgs[sl][c]);
                }
        }
    }

    // ---------------- L1: K=320 (5 chunks of 64), masked staging, prefetched
    floatx16 accO[4], accG[4];
#pragma unroll
    for (int i = 0; i < 4; ++i) { accO[i] = (floatx16)(0.f); accG[i] = (floatx16)(0.f); }

    const uint32_t* arow = xp + (size_t)(s0 + row) * 320 + k0;
    uint32_t pfw[32];
    int ic = half_id * 2;
#pragma unroll
    for (int q = 0; q < 8; ++q)
        *(uint4*)&pfw[q * 4] = *(const uint4*)(arow + ic * 64 + q * 4);

#pragma unroll 1
    for (int i = 0; i < 5; ++i) {
        __syncthreads();                       // prev chunk reads (and att Apk reads) done
        {
            const int kb = ic * 64 + k0;
            float mA = 1.f, mB = 1.f;
            if (MASK && ic != 0) {
                mA = mgs[row][64 + ((kb - 64) >> 4)];
                mB = mgs[row][64 + ((kb - 48) >> 4)];
            }
#pragma unroll
            for (int q = 0; q < 4; ++q) {
                half8 hh, ll;
                if (MASK && ic == 0) {
                    const float4 m0q = *(const float4*)&mgs[row][kb + q * 8];
                    const float4 m1q = *(const float4*)&mgs[row][kb + q * 8 + 4];
                    const float mm[8] = {m0q.x, m0q.y, m0q.z, m0q.w, m1q.x, m1q.y, m1q.z, m1q.w};
#pragma unroll
                    for (int j = 0; j < 8; ++j) {
                        half_t h, l; unpack2(pfw[q * 8 + j], h, l);
                        const float v = ((float)h + (float)l) * mm[j];
                        const half_t nh = (half_t)v;
                        hh[j] = nh; ll[j] = (half_t)(v - (float)nh);
                    }
                } else if (MASK) {
                    const float m = (q < 2) ? mA : mB;
#pragma unroll
                    for (int j = 0; j < 8; ++j) {
                        half_t h, l; unpack2(pfw[q * 8 + j], h, l);
                        const float v = ((float)h + (float)l) * m;
                        const half_t nh = (half_t)v;
                        hh[j] = nh; ll[j] = (half_t)(v - (float)nh);
                    }
                } else {
#pragma unroll
                    for (int j = 0; j < 8; ++j) { half_t h, l; unpack2(pfw[q * 8 + j], h, l); hh[j] = h; ll[j] = l; }
                }
                *(half8*)&As_h[row][k0 + q * 8] = hh;
                *(half8*)&As_l[row][k0 + q * 8] = ll;
            }
        }
        __syncthreads();
        const int icn = (ic + 1 == 5) ? 0 : ic + 1;
        if (i < 4) {
#pragma unroll
            for (int q = 0; q < 8; ++q)
                *(uint4*)&pfw[q * 4] = *(const uint4*)(arow + icn * 64 + q * 4);
        }
#pragma unroll
        for (int sl4 = 0; sl4 < 4; ++sl4) {
            const int kq = ic * 8 + sl4 * 2 + k8;
            const size_t wo = (size_t)(kq * 256 + no + n32) * 8;
            const half8 bo_h = *(const half8*)(Wh + wo);
            const half8 bo_l = *(const half8*)(Wl + wo);
            const half8 bg_h = *(const half8*)(Wh + wo + 1024);
            const half8 bg_l = *(const half8*)(Wl + wo + 1024);
#pragma unroll
            for (int mt = 0; mt < 4; ++mt) {
                const half8 a_h = *(const half8*)&As_h[mt * 32 + n32][sl4 * 16 + k8 * 8];
                const half8 a_l = *(const half8*)&As_l[mt * 32 + n32][sl4 * 16 + k8 * 8];
                MFMA32(a_h, bo_h, accO[mt]); MFMA32(a_h, bg_h, accG[mt]);
                MFMA32(a_l, bo_h, accO[mt]); MFMA32(a_l, bg_h, accG[mt]);
                MFMA32(a_h, bo_l, accO[mt]); MFMA32(a_h, bg_l, accG[mt]);
            }
        }
        ic = icn;
    }
    __syncthreads();   // all As/mgs reads complete before H overlay writes

    // L1 epilogue -> H planes
    {
        const int c = no + n32;
        float sc_o, sh_o, sc_g, sh_g;
        bn_fold(bn1, b1, c, sc_o, sh_o);
        bn_fold(bn1, b1, c + 128, sc_g, sh_g);
#pragma unroll
        for (int mt = 0; mt < 4; ++mt)
#pragma unroll
            for (int reg = 0; reg < 16; ++reg) {
                const int sl = mt * 32 + (reg & 3) + 8 * (reg >> 2) + 4 * k8;
                const float y = glu_val(accO[mt][reg], accG[mt][reg], sc_o, sh_o, sc_g, sh_g);
                const half_t nh = (half_t)y;
                H_h[sl][c] = nh; H_l[sl][c] = (half_t)(y - (float)nh);
            }
    }
    __syncthreads();

    // ---------------- L2, L3
#pragma unroll 1
    for (int layer = 0; layer < 2; ++layer) {
        const float* bb = layer ? b3 : b2;
        const float* bn = layer ? bn3 : bn2;
        const size_t off = layer ? w3_off : (size_t)81920;
#pragma unroll
        for (int i = 0; i < 4; ++i) { accO[i] = (floatx16)(0.f); accG[i] = (floatx16)(0.f); }
        layer_accum(H_h, H_l, Wh, Wl, off, n32, k8, no, half_id * 4, accO, accG);
        __syncthreads();
        {
            const int c = no + n32;
            float sc_o, sh_o, sc_g, sh_g;
            bn_fold(bn, bb, c, sc_o, sh_o);
            bn_fold(bn, bb, c + 128, sc_g, sh_g);
#pragma unroll
            for (int mt = 0; mt < 4; ++mt)
#pragma unroll
                for (int reg = 0; reg < 16; ++reg) {
                    const int sl = mt * 32 + (reg & 3) + 8 * (reg >> 2) + 4 * k8;
                    const float res = (float)H_h[sl][c] + (float)H_l[sl][c];
                    const float y = (glu_val(accO[mt][reg], accG[mt][reg], sc_o, sh_o, sc_g, sh_g) + res) * RES_SCALE_C;
                    const half_t nh = (half_t)y;
                    H_h[sl][c] = nh; H_l[sl][c] = (half_t)(y - (float)nh);
                }
        }
        __syncthreads();
    }

    // ---------------- L4 -> global outputs
#pragma unroll
    for (int i = 0; i < 4; ++i) { accO[i] = (floatx16)(0.f); accG[i] = (floatx16)(0.f); }
    layer_accum(H_h, H_l, Wh, Wl, w4_off, n32, k8, no, half_id * 4, accO, accG);
    {
        const int c = no + n32;
        float sc_o, sh_o, sc_g, sh_g;
        bn_fold(bn4, b4, c, sc_o, sh_o);
        bn_fold(bn4, b4, c + 128, sc_g, sh_g);
        if (w < 2) {
            if (wmode_last != 1) {
#pragma unroll
                for (int mt = 0; mt < 4; ++mt)
#pragma unroll
                    for (int reg = 0; reg < 16; ++reg) {
                        const int sl = mt * 32 + (reg & 3) + 8 * (reg >> 2) + 4 * k8;
                        const float res = (float)H_h[sl][c] + (float)H_l[sl][c];
                        const float y = (glu_val(accO[mt][reg], accG[mt][reg], sc_o, sh_o, sc_g, sh_g) + res) * RES_SCALE_C;
                        const float d = fmaxf(y, 0.f);
                        float* dp = ds + (size_t)(s0 + sl) * 64 + c;
                        *dp = (wmode_last == 2) ? d : (*dp + d);
                    }
            }
        } else {
#pragma unroll
            for (int mt = 0; mt < 4; ++mt)
#pragma unroll
                for (int reg = 0; reg < 16; ++reg) {
                    const int sl = mt * 32 + (reg & 3) + 8 * (reg >> 2) + 4 * k8;
                    const float res = (float)H_h[sl][c] + (float)H_l[sl][c];
                    const float y = (glu_val(accO[mt][reg], accG[mt][reg], sc_o, sh_o, sc_g, sh_g) + res) * RES_SCALE_C;
                    avp[(size_t)(s0 + sl) * 64 + (c - 64)] = pack2(y);
                }
        }
    }
}

// ---------------- final 64 -> 1 ----------------
__global__ void final_kernel(const float* __restrict__ dsum, const float* __restrict__ out_W,
                             const float* __restrict__ out_b, float* __restrict__ out)
{
    const int s = blockIdx.x * 256 + threadIdx.x;
    float acc = out_b[0];
    const float4* dp = (const float4*)(dsum + (size_t)s * 64);
    const float4* wp = (const float4*)out_W;
#pragma unroll
    for (int q = 0; q < 16; ++q) {
        const float4 d = dp[q];
        const float4 ww = wp[q];
        acc += d.x * ww.x + d.y * ww.y + d.z * ww.z + d.w * ww.w;
    }
    out[s] = acc;
}

// ---------------- launch ----------------
extern "C" void kernel_launch(void* const* d_in, const int* in_sizes, int n_in,
                              void* d_out, int out_size, void* d_ws, size_t ws_size,
                              hipStream_t stream)
{
    const float* x_num  = (const float*)d_in[0];
    const int*   x_cat  = (const int*)d_in[1];
    const float* emb_W  = (const float*)d_in[2];
    const float* in_bn  = (const float*)d_in[3];
    const float* sh_W0  = (const float*)d_in[4];
    const float* sh_b0  = (const float*)d_in[5];
    const float* sh_bn0 = (const float*)d_in[6];
    const float* sh_W1  = (const float*)d_in[7];
    const float* sh_b1  = (const float*)d_in[8];
    const float* sh_bn1 = (const float*)d_in[9];
    const float* init_W = (const float*)d_in[10];
    const float* init_b = (const float*)d_in[11];
    const float* init_bn= (const float*)d_in[12];
    const float* step_W = (const float*)d_in[13];
    const float* step_b = (const float*)d_in[14];
    const float* step_bn= (const float*)d_in[15];
    const float* att_W  = (const float*)d_in[16];
    const float* att_b  = (const float*)d_in[17];
    const float* att_bn = (const float*)d_in[18];
    const float* out_W  = (const float*)d_in[19];
    const float* out_b  = (const float*)d_in[20];

    const size_t B = B_TOT;
    char* p = (char*)d_ws;
    uint32_t* xp  = (uint32_t*)p;  p += B * 320 * 4;
    uint32_t* avp = (uint32_t*)p;  p += B * 64 * 4;
    half_t* Wh    = (half_t*)p;    p += 507904 * 2;
    half_t* Wl    = (half_t*)p;    p += 507904 * 2;
    half_t* aWh   = (half_t*)p;    p += 25600 * 2;
    half_t* aWl   = (half_t*)p;    p += 25600 * 2;
    float* pri    = (float*)p;     p += B * 80 * 4;
    float* ds     = (float*)p;     p += B * 64 * 4;

    wsplit_kernel<<<1984, 256, 0, stream>>>(sh_W0, sh_W1, init_W, step_W, Wh, Wl);
    wsplit_att_kernel<<<320, 80, 0, stream>>>(att_W, aWh, aWl);
    embed_bn_kernel<<<(B_TOT * 320) / 256, 256, 0, stream>>>(x_num, x_cat, emb_W, in_bn, xp);

    const int GB = B_TOT / 128;   // 512 blocks
    // W plane offsets (halves): sh_W0=0, sh_W1=81920, init0=114688, init1=147456, step j=180224+j*32768
    ft_chain<false><<<GB, 256, 0, stream>>>(xp, avp, Wh, Wl,
                                            nullptr, nullptr, nullptr, nullptr, nullptr,
                                            sh_b0, sh_bn0, sh_b1, sh_bn1,
                                            init_b, init_bn, init_b + 256, init_bn + 1024,
                                            (size_t)114688, (size_t)147456, ds, 1, 0);
    for (int st = 0; st < 5; ++st) {
        const size_t w3 = 180224 + (size_t)(st * 2 + 0) * 32768;
        const size_t w4 = 180224 + (size_t)(st * 2 + 1) * 32768;
        ft_chain<true><<<GB, 256, 0, stream>>>(xp, avp, Wh, Wl,
                                               aWh + st * 5120, aWl + st * 5120,
                                               att_b + st * 80, att_bn + st * 320, pri,
                                               sh_b0, sh_bn0, sh_b1, sh_bn1,
                                               step_b + (st * 2 + 0) * 256, step_bn + (st * 2 + 0) * 1024,
                                               step_b + (st * 2 + 1) * 256, step_bn + (st * 2 + 1) * 1024,
                                               w3, w4, ds, st == 0 ? 2 : 3, st);
    }
    final_kernel<<<B_TOT / 256, 256, 0, stream>>>(ds, out_W, out_b, (float*)d_out);
}